// Round 2
// baseline (405.084 us; speedup 1.0000x reference)
//
#include <hip/hip_runtime.h>
#include <hip/hip_bf16.h>

typedef unsigned short u16;
typedef short bf16x8 __attribute__((ext_vector_type(8)));
typedef float f32x4 __attribute__((ext_vector_type(4)));

#define B_ 4
#define S_ 1024
#define E_ 1024
#define H_ 16
#define FF_ 4096
#define D_ 64
#define M_ 4096  /* B*S */

__device__ __forceinline__ u16 f2bf(float f) {
  unsigned int u = __builtin_bit_cast(unsigned int, f);
  u += 0x7fffu + ((u >> 16) & 1u);   // RNE
  return (u16)(u >> 16);
}
__device__ __forceinline__ float bf2f(u16 v) {
  unsigned int u = ((unsigned int)v) << 16;
  return __builtin_bit_cast(float, u);
}

__device__ __forceinline__ void gld_lds16(const void* g, void* l) {
  __builtin_amdgcn_global_load_lds((__attribute__((address_space(1))) void*)g,
                                   (__attribute__((address_space(3))) void*)l,
                                   16, 0, 0);
}

// ---------------------------------------------------------------------------
// Weight cast+transpose: W (K x N fp32) -> Wt (N x K bf16), all 6 weights
// ---------------------------------------------------------------------------
__global__ void __launch_bounds__(256) cast_transpose_all(
    const float* __restrict__ wq, const float* __restrict__ wk,
    const float* __restrict__ wv, const float* __restrict__ wo,
    const float* __restrict__ w1, const float* __restrict__ w2,
    u16* __restrict__ wt) {
  int bid = blockIdx.x;
  const float* src; u16* dst; int K, N; int local;
  if (bid < 4096) {
    int wsel = bid >> 10; local = bid & 1023; K = 1024; N = 1024;
    src = wsel == 0 ? wq : wsel == 1 ? wk : wsel == 2 ? wv : wo;
    dst = wt + (size_t)wsel * 1024 * 1024;
  } else if (bid < 8192) {
    local = bid - 4096; K = 1024; N = 4096; src = w1;
    dst = wt + (size_t)4 * 1024 * 1024;
  } else {
    local = bid - 8192; K = 4096; N = 1024; src = w2;
    dst = wt + (size_t)8 * 1024 * 1024;
  }
  int tiles_n = N >> 5;
  int n0 = (local % tiles_n) << 5, k0 = (local / tiles_n) << 5;
  __shared__ float tl[32][33];
  int tx = threadIdx.x & 31, ty = threadIdx.x >> 5;
#pragma unroll
  for (int i = 0; i < 4; ++i)
    tl[ty + i * 8][tx] = src[(size_t)(k0 + ty + i * 8) * N + n0 + tx];
  __syncthreads();
#pragma unroll
  for (int i = 0; i < 4; ++i)
    dst[(size_t)(n0 + ty + i * 8) * K + k0 + tx] = f2bf(tl[tx][ty + i * 8]);
}

// ---------------------------------------------------------------------------
// mask -> interleaved additive bf16 bias; gnn -> bf16 row-major
// biasI[b][kt][q][c][f] = (mask[b][q][kt*64+f*16+c]==0 ? -30000 : 0)
// ---------------------------------------------------------------------------
__global__ void __launch_bounds__(256) cast_maskgnn(
    const float* __restrict__ mask, const float* __restrict__ gnn,
    u16* __restrict__ biasI, u16* __restrict__ gnnbf) {
  int row = blockIdx.x;             // b*1024 + q
  int b = row >> 10, q = row & 1023;
  int t = threadIdx.x;
  const float* mrow = mask + ((size_t)row << 10);
  const float* grow = gnn + ((size_t)row << 10);
  float4 mv = *(const float4*)(mrow + t * 4);
  float4 gv = *(const float4*)(grow + t * 4);
  ushort4 g4;
  g4.x = f2bf(gv.x); g4.y = f2bf(gv.y); g4.z = f2bf(gv.z); g4.w = f2bf(gv.w);
  *(ushort4*)(gnnbf + ((size_t)row << 10) + t * 4) = g4;
  float mvv[4] = {mv.x, mv.y, mv.z, mv.w};
#pragma unroll
  for (int i = 0; i < 4; ++i) {
    int kv = t * 4 + i;
    int kt = kv >> 6, w6 = kv & 63, c = w6 & 15, f = w6 >> 4;
    u16 bval = (mvv[i] == 0.f) ? f2bf(-30000.f) : 0;
    biasI[((size_t)(b * 16 + kt) * 1024 + q) * 64 + c * 4 + f] = bval;
  }
}

// ---------------------------------------------------------------------------
// LayerNorm: fp32 (M x 1024) -> bf16. One block per row.
// ---------------------------------------------------------------------------
__global__ void __launch_bounds__(256) ln_kernel(
    const float* __restrict__ x, const float* __restrict__ g,
    const float* __restrict__ bt, u16* __restrict__ out) {
  int row = blockIdx.x, t = threadIdx.x;
  const float* xr = x + (size_t)row * 1024;
  float4 v = *(const float4*)(xr + t * 4);
  float s = v.x + v.y + v.z + v.w;
  float q = v.x * v.x + v.y * v.y + v.z * v.z + v.w * v.w;
#pragma unroll
  for (int off = 1; off < 64; off <<= 1) {
    s += __shfl_xor(s, off);
    q += __shfl_xor(q, off);
  }
  __shared__ float sb[4], qb[4];
  int w = t >> 6, l = t & 63;
  if (l == 0) { sb[w] = s; qb[w] = q; }
  __syncthreads();
  s = sb[0] + sb[1] + sb[2] + sb[3];
  q = qb[0] + qb[1] + qb[2] + qb[3];
  float mean = s * (1.f / 1024.f);
  float var = q * (1.f / 1024.f) - mean * mean;
  float rs = rsqrtf(var + 1e-5f);
  float4 gv = *(const float4*)(g + t * 4);
  float4 bv = *(const float4*)(bt + t * 4);
  ushort4 o;
  o.x = f2bf((v.x - mean) * rs * gv.x + bv.x);
  o.y = f2bf((v.y - mean) * rs * gv.y + bv.y);
  o.z = f2bf((v.z - mean) * rs * gv.z + bv.z);
  o.w = f2bf((v.w - mean) * rs * gv.w + bv.w);
  *(ushort4*)(out + (size_t)row * 1024 + t * 4) = o;
}

// ---------------------------------------------------------------------------
// GEMM core 128x128, BK=64: C = A(MxK) @ Bt(NxK)^T, bf16 in fp32 acc
// ---------------------------------------------------------------------------
__device__ __forceinline__ void gemm_core_128(
    const u16* __restrict__ A, const u16* __restrict__ Bt, int Kdim,
    int bm, int bn, u16* ldsA, u16* ldsB, f32x4 acc[4][4]) {
  const int tid = threadIdx.x;
  const int w = tid >> 6, l = tid & 63;
  const int wm = (w >> 1) << 6, wn = (w & 1) << 6;
  const int lrow = l >> 3;
  const int cg = (l & 7) ^ lrow;
  const size_t arow0 = (size_t)(bm << 7) * Kdim;
  const size_t brow0 = (size_t)(bn << 7) * Kdim;
  for (int kt = 0; kt < Kdim; kt += 64) {
#pragma unroll
    for (int i = 0; i < 4; ++i) {
      int c = (w << 2) + i;
      int row = (c << 3) + lrow;
      gld_lds16(A + arow0 + (size_t)row * Kdim + kt + (cg << 3), ldsA + (c << 9));
      gld_lds16(Bt + brow0 + (size_t)row * Kdim + kt + (cg << 3), ldsB + (c << 9));
    }
    __syncthreads();
    bf16x8 af[2][4], bfr[2][4];
    const int rr = l & 15;
    const int kgb = l >> 4;
#pragma unroll
    for (int ks = 0; ks < 2; ++ks) {
      const int kg = kgb + (ks << 2);
#pragma unroll
      for (int f = 0; f < 4; ++f) {
        int ra = wm + (f << 4) + rr;
        af[ks][f] = *(const bf16x8*)(ldsA + (ra << 6) + ((kg ^ (ra & 7)) << 3));
        int rb = wn + (f << 4) + rr;
        bfr[ks][f] = *(const bf16x8*)(ldsB + (rb << 6) + ((kg ^ (rb & 7)) << 3));
      }
    }
#pragma unroll
    for (int fm = 0; fm < 4; ++fm)
#pragma unroll
      for (int fn = 0; fn < 4; ++fn)
#pragma unroll
        for (int ks = 0; ks < 2; ++ks)
          acc[fm][fn] = __builtin_amdgcn_mfma_f32_16x16x32_bf16(
              af[ks][fm], bfr[ks][fn], acc[fm][fn], 0, 0, 0);
    __syncthreads();
  }
}

#define ACC_INIT()                        \
  f32x4 acc[4][4];                        \
  { f32x4 zf = {0.f, 0.f, 0.f, 0.f};      \
_Pragma("unroll")                         \
    for (int a = 0; a < 4; ++a)           \
_Pragma("unroll")                         \
      for (int bb = 0; bb < 4; ++bb) acc[a][bb] = zf; }

#define EPI_SETUP()                                     \
  const int w = threadIdx.x >> 6, l = threadIdx.x & 63; \
  const int wm = (w >> 1) << 6, wn = (w & 1) << 6;

// --- QKV: z=0 Q[b,h,s,d], z=1 K[b,h,s,d], z=2 Vt[b,e,kv] --------------------
__global__ void __launch_bounds__(256) gemm_qkv(
    const u16* __restrict__ nx, const u16* __restrict__ wt,
    const float* __restrict__ bq, const float* __restrict__ bk,
    const float* __restrict__ bv, u16* __restrict__ qkv) {
  __shared__ __attribute__((aligned(16))) u16 lds[2 * 128 * 64];
  ACC_INIT();
  int z = blockIdx.z;
  const u16* Bt = wt + (size_t)z * 1024 * 1024;
  const float* bias = z == 0 ? bq : z == 1 ? bk : bv;
  u16* out = qkv + (size_t)z * M_ * 1024;
  gemm_core_128(nx, Bt, 1024, blockIdx.x, blockIdx.y, lds, lds + 128 * 64, acc);
  EPI_SETUP();
#pragma unroll
  for (int fm = 0; fm < 4; ++fm)
#pragma unroll
    for (int fn = 0; fn < 4; ++fn)
#pragma unroll
      for (int j = 0; j < 4; ++j) {
        int row = (blockIdx.x << 7) + wm + (fm << 4) + ((l >> 4) << 2) + j;
        int col = (blockIdx.y << 7) + wn + (fn << 4) + (l & 15);
        float v = acc[fm][fn][j] + bias[col];
        int b = row >> 10, s = row & 1023;
        if (z == 2) {
          out[((size_t)b << 20) + ((size_t)col << 10) + s] = f2bf(v);
        } else {
          int h = col >> 6, d = col & 63;
          out[(((size_t)(b * 16 + h) << 10) + s) * 64 + d] = f2bf(v);
        }
      }
}

// --- gnnV: xvg[b,q,e] = gnnbf[b] @ Vt[b]^T (bf16 out) ------------------------
__global__ void __launch_bounds__(256) gemm_gnnv(
    const u16* __restrict__ gnnbf, const u16* __restrict__ vt,
    u16* __restrict__ xvg) {
  __shared__ __attribute__((aligned(16))) u16 lds[2 * 128 * 64];
  ACC_INIT();
  int b = blockIdx.z;
  const u16* A = gnnbf + ((size_t)b << 20);
  const u16* Bt = vt + ((size_t)b << 20);
  u16* out = xvg + ((size_t)b << 20);
  gemm_core_128(A, Bt, 1024, blockIdx.x, blockIdx.y, lds, lds + 128 * 64, acc);
  EPI_SETUP();
#pragma unroll
  for (int fm = 0; fm < 4; ++fm)
#pragma unroll
    for (int fn = 0; fn < 4; ++fn)
#pragma unroll
      for (int j = 0; j < 4; ++j) {
        int row = (blockIdx.x << 7) + wm + (fm << 4) + ((l >> 4) << 2) + j;
        int col = (blockIdx.y << 7) + wn + (fn << 4) + (l & 15);
        out[((size_t)row << 10) + col] = f2bf(acc[fm][fn][j]);
      }
}

// --- Wo: x1 = x + xv@Wo + bo (fp32 out) --------------------------------------
__global__ void __launch_bounds__(256) gemm_wo(
    const u16* __restrict__ xv, const u16* __restrict__ wt,
    const float* __restrict__ bo, const float* __restrict__ xres,
    float* __restrict__ x1) {
  __shared__ __attribute__((aligned(16))) u16 lds[2 * 128 * 64];
  ACC_INIT();
  gemm_core_128(xv, wt, 1024, blockIdx.x, blockIdx.y, lds, lds + 128 * 64, acc);
  EPI_SETUP();
#pragma unroll
  for (int fm = 0; fm < 4; ++fm)
#pragma unroll
    for (int fn = 0; fn < 4; ++fn)
#pragma unroll
      for (int j = 0; j < 4; ++j) {
        int row = (blockIdx.x << 7) + wm + (fm << 4) + ((l >> 4) << 2) + j;
        int col = (blockIdx.y << 7) + wn + (fn << 4) + (l & 15);
        size_t idx = ((size_t)row << 10) + col;
        x1[idx] = acc[fm][fn][j] + bo[col] + xres[idx];
      }
}

// --- W1 (per M-half): ff1 = gelu(h@W1 + bf1) bf16 ----------------------------
__global__ void __launch_bounds__(256) gemm_w1(
    const u16* __restrict__ hb, const u16* __restrict__ wt,
    const float* __restrict__ bf1, u16* __restrict__ ff1) {
  __shared__ __attribute__((aligned(16))) u16 lds[2 * 128 * 64];
  ACC_INIT();
  gemm_core_128(hb, wt, 1024, blockIdx.x, blockIdx.y, lds, lds + 128 * 64, acc);
  EPI_SETUP();
#pragma unroll
  for (int fm = 0; fm < 4; ++fm)
#pragma unroll
    for (int fn = 0; fn < 4; ++fn)
#pragma unroll
      for (int j = 0; j < 4; ++j) {
        int row = (blockIdx.x << 7) + wm + (fm << 4) + ((l >> 4) << 2) + j;
        int col = (blockIdx.y << 7) + wn + (fn << 4) + (l & 15);
        float v = acc[fm][fn][j] + bf1[col];
        float ge = 0.5f * v * (1.f + erff(v * 0.70710678118654752f));
        ff1[((size_t)row << 12) + col] = f2bf(ge);
      }
}

// --- W2 (per M-half): out = x1 + ff1@W2 + bf2 (fp32, K=4096) -----------------
__global__ void __launch_bounds__(256) gemm_w2(
    const u16* __restrict__ ff1, const u16* __restrict__ wt,
    const float* __restrict__ bf2, const float* __restrict__ x1,
    float* __restrict__ out) {
  __shared__ __attribute__((aligned(16))) u16 lds[2 * 128 * 64];
  ACC_INIT();
  gemm_core_128(ff1, wt, 4096, blockIdx.x, blockIdx.y, lds, lds + 128 * 64, acc);
  EPI_SETUP();
#pragma unroll
  for (int fm = 0; fm < 4; ++fm)
#pragma unroll
    for (int fn = 0; fn < 4; ++fn)
#pragma unroll
      for (int j = 0; j < 4; ++j) {
        int row = (blockIdx.x << 7) + wm + (fm << 4) + ((l >> 4) << 2) + j;
        int col = (blockIdx.y << 7) + wn + (fn << 4) + (l & 15);
        size_t idx = ((size_t)row << 10) + col;
        out[idx] = acc[fm][fn][j] + bf2[col] + x1[idx];
      }
}

// ---------------------------------------------------------------------------
// Flash attention: grid (8 qt, 16 h, 4 b); 4 waves x 32 q-rows; KV tile 64.
// Double-buffered K/Vt staging via global_load_lds; additive bf16 mask bias.
// Output: xv[b,s,e] = softmax@V + xvg (gnn@V precomputed).
// ---------------------------------------------------------------------------
__global__ void __launch_bounds__(256, 2) attn_kernel(
    const u16* __restrict__ Q, const u16* __restrict__ K,
    const u16* __restrict__ Vt, const u16* __restrict__ biasI,
    const u16* __restrict__ xvg, u16* __restrict__ xv) {
  const int qt = blockIdx.x, h = blockIdx.y, b = blockIdx.z;
  const int tid = threadIdx.x, w = tid >> 6, l = tid & 63;
  __shared__ __attribute__((aligned(16))) u16 kbuf[2][64 * 64];
  __shared__ __attribute__((aligned(16))) u16 vbuf[2][64 * 64];
  __shared__ __attribute__((aligned(16))) u16 pbuf[4][32 * 64];
  const size_t bh = ((size_t)(b * 16 + h)) << 16;
  const u16* Qb = Q + bh;
  const u16* Kb = K + bh;
  const u16* Vtb = Vt + ((size_t)b << 20) + ((size_t)(h * 64) << 10);
  const u16* biasb = biasI + ((size_t)b << 20);
  const int q0 = (qt << 7) + (w << 5);
  const int lrow = l >> 3, cg = (l & 7) ^ lrow;
  const int l4 = l >> 4, lo = l & 15;
  u16* p_w = pbuf[w];

  // Q fragments in registers (A-operand)
  bf16x8 qf[2][2];
#pragma unroll
  for (int m = 0; m < 2; ++m)
#pragma unroll
    for (int ks = 0; ks < 2; ++ks)
      qf[m][ks] = *(const bf16x8*)(Qb + ((size_t)(q0 + m * 16 + lo) << 6) +
                                   l4 * 8 + ks * 32);

  float run_m[2][4], run_l[2][4];
  f32x4 osoft[2][4];
  f32x4 zf = {0.f, 0.f, 0.f, 0.f};
#pragma unroll
  for (int m = 0; m < 2; ++m)
#pragma unroll
    for (int j = 0; j < 4; ++j) { run_m[m][j] = -1e30f; run_l[m][j] = 0.f; }
#pragma unroll
  for (int m = 0; m < 2; ++m)
#pragma unroll
    for (int fd = 0; fd < 4; ++fd) osoft[m][fd] = zf;

#define STAGE(T, BUF)                                                          \
  {                                                                            \
    int kv0s = (T) << 6;                                                       \
    u16* kd = &kbuf[BUF][0];                                                   \
    u16* vd = &vbuf[BUF][0];                                                   \
    _Pragma("unroll") for (int i = 0; i < 2; ++i) {                            \
      int c = (w << 1) + i;                                                    \
      gld_lds16(Kb + ((size_t)(kv0s + (c << 3) + lrow) << 6) + (cg << 3),      \
                kd + (c << 9));                                                \
      gld_lds16(Vtb + ((size_t)((c << 3) + lrow) << 10) + kv0s + (cg << 3),    \
                vd + (c << 9));                                                \
    }                                                                          \
  }

  STAGE(0, 0);
  __syncthreads();

  for (int t = 0; t < 16; ++t) {
    const int cur = t & 1;
    if (t < 15) STAGE(t + 1, cur ^ 1);
    const int kv0 = t << 6;
    const u16* kb_ = &kbuf[cur][0];
    const u16* vb_ = &vbuf[cur][0];
    // bias loads (issued early; independent of LDS)
    ushort4 bv4[2][4];
#pragma unroll
    for (int m = 0; m < 2; ++m)
#pragma unroll
      for (int j = 0; j < 4; ++j)
        bv4[m][j] = *(const ushort4*)(
            biasb + (((size_t)(t * 1024 + q0 + m * 16 + l4 * 4 + j)) << 6) +
            lo * 4);
    // QK^T
    f32x4 sacc[2][4];
#pragma unroll
    for (int m = 0; m < 2; ++m)
#pragma unroll
      for (int fn = 0; fn < 4; ++fn) sacc[m][fn] = zf;
#pragma unroll
    for (int ks = 0; ks < 2; ++ks) {
      const int kg = l4 + (ks << 2);
      bf16x8 kf[4];
#pragma unroll
      for (int fn = 0; fn < 4; ++fn) {
        int rk = (fn << 4) + lo;
        kf[fn] = *(const bf16x8*)(kb_ + (rk << 6) + ((kg ^ (rk & 7)) << 3));
      }
#pragma unroll
      for (int m = 0; m < 2; ++m)
#pragma unroll
        for (int fn = 0; fn < 4; ++fn)
          sacc[m][fn] = __builtin_amdgcn_mfma_f32_16x16x32_bf16(
              qf[m][ks], kf[fn], sacc[m][fn], 0, 0, 0);
    }
    // masked online softmax
#pragma unroll
    for (int m = 0; m < 2; ++m)
#pragma unroll
      for (int j = 0; j < 4; ++j) {
        float s0 = sacc[m][0][j] * 0.125f + bf2f(bv4[m][j].x);
        float s1 = sacc[m][1][j] * 0.125f + bf2f(bv4[m][j].y);
        float s2 = sacc[m][2][j] * 0.125f + bf2f(bv4[m][j].z);
        float s3 = sacc[m][3][j] * 0.125f + bf2f(bv4[m][j].w);
        float tm = fmaxf(fmaxf(s0, s1), fmaxf(s2, s3));
#pragma unroll
        for (int off = 1; off < 16; off <<= 1) tm = fmaxf(tm, __shfl_xor(tm, off));
        float nm = fmaxf(run_m[m][j], tm);
        float sc = __expf(run_m[m][j] - nm);
        run_m[m][j] = nm;
        float p0 = __expf(s0 - nm), p1 = __expf(s1 - nm);
        float p2 = __expf(s2 - nm), p3 = __expf(s3 - nm);
        sacc[m][0][j] = p0; sacc[m][1][j] = p1;
        sacc[m][2][j] = p2; sacc[m][3][j] = p3;
        float rs = (p0 + p1) + (p2 + p3);
#pragma unroll
        for (int off = 1; off < 16; off <<= 1) rs += __shfl_xor(rs, off);
        run_l[m][j] = run_l[m][j] * sc + rs;
#pragma unroll
        for (int fd = 0; fd < 4; ++fd) osoft[m][fd][j] *= sc;
      }
    // P -> per-wave LDS (swizzled)
#pragma unroll
    for (int m = 0; m < 2; ++m)
#pragma unroll
      for (int fn = 0; fn < 4; ++fn)
#pragma unroll
        for (int j = 0; j < 4; ++j) {
          int prow = (m << 4) + (l4 << 2) + j;
          int pcol = (fn << 4) + lo;
          p_w[(prow << 6) + (pcol ^ ((prow & 7) << 3))] = f2bf(sacc[m][fn][j]);
        }
    // PV
#pragma unroll
    for (int ks = 0; ks < 2; ++ks) {
      const int kg = l4 + (ks << 2);
      bf16x8 pf[2], vf[4];
#pragma unroll
      for (int m = 0; m < 2; ++m) {
        int pr = (m << 4) + lo;
        pf[m] = *(const bf16x8*)(p_w + (pr << 6) + ((kg ^ (pr & 7)) << 3));
      }
#pragma unroll
      for (int fd = 0; fd < 4; ++fd) {
        int rd = (fd << 4) + lo;
        vf[fd] = *(const bf16x8*)(vb_ + (rd << 6) + ((kg ^ (rd & 7)) << 3));
      }
#pragma unroll
      for (int m = 0; m < 2; ++m)
#pragma unroll
        for (int fd = 0; fd < 4; ++fd)
          osoft[m][fd] = __builtin_amdgcn_mfma_f32_16x16x32_bf16(
              pf[m], vf[fd], osoft[m][fd], 0, 0, 0);
    }
    __syncthreads();
  }
  // epilogue: add gnn@V and store
#pragma unroll
  for (int m = 0; m < 2; ++m)
#pragma unroll
    for (int fd = 0; fd < 4; ++fd)
#pragma unroll
      for (int j = 0; j < 4; ++j) {
        int qrow = q0 + (m << 4) + (l4 << 2) + j;
        int e = (h << 6) + (fd << 4) + lo;
        size_t idx = (((size_t)(b * 1024 + qrow)) << 10) + e;
        float o = osoft[m][fd][j] / run_l[m][j] + bf2f(xvg[idx]);
        xv[idx] = f2bf(o);
      }
#undef STAGE
}

// ---------------------------------------------------------------------------
extern "C" void kernel_launch(void* const* d_in, const int* in_sizes, int n_in,
                              void* d_out, int out_size, void* d_ws, size_t ws_size,
                              hipStream_t stream) {
  (void)in_sizes; (void)n_in; (void)out_size; (void)ws_size;
  const float* x   = (const float*)d_in[0];
  const float* mask= (const float*)d_in[1];
  const float* gnn = (const float*)d_in[2];
  const float* Wq  = (const float*)d_in[3];
  const float* bq  = (const float*)d_in[4];
  const float* Wk  = (const float*)d_in[5];
  const float* bk  = (const float*)d_in[6];
  const float* Wv  = (const float*)d_in[7];
  const float* bv  = (const float*)d_in[8];
  const float* Wo  = (const float*)d_in[9];
  const float* bo  = (const float*)d_in[10];
  const float* g1  = (const float*)d_in[11];
  const float* b1  = (const float*)d_in[12];
  const float* g2  = (const float*)d_in[13];
  const float* b2  = (const float*)d_in[14];
  const float* W1  = (const float*)d_in[15];
  const float* bf1 = (const float*)d_in[16];
  const float* W2  = (const float*)d_in[17];
  const float* bf2 = (const float*)d_in[18];
  float* out = (float*)d_out;

  char* ws = (char*)d_ws;
  const size_t MB = 1024 * 1024;
  // layout (MB): 0-24 wt | 24-32 nx -> xv | 32-40 Q | 40-48 K | 48-56 Vt
  // | 56-64 biasI | 64-72 gnnbf -> hbuf | 72-80 xvg
  // post-attn: x1 fp32 48-64 | ff1-half 24-40
  u16*  wt    = (u16*)(ws);
  u16*  nx    = (u16*)(ws + 24 * MB);
  u16*  xvbuf = (u16*)(ws + 24 * MB);
  u16*  qkv   = (u16*)(ws + 32 * MB);
  u16*  vt    = (u16*)(ws + 48 * MB);
  u16*  biasI = (u16*)(ws + 56 * MB);
  u16*  gnnbf = (u16*)(ws + 64 * MB);
  u16*  hbuf  = (u16*)(ws + 64 * MB);
  u16*  xvg   = (u16*)(ws + 72 * MB);
  float* x1   = (float*)(ws + 48 * MB);
  u16*  ff1h  = (u16*)(ws + 24 * MB);

  cast_transpose_all<<<12288, 256, 0, stream>>>(Wq, Wk, Wv, Wo, W1, W2, wt);
  ln_kernel<<<4096, 256, 0, stream>>>(x, g1, b1, nx);
  cast_maskgnn<<<4096, 256, 0, stream>>>(mask, gnn, biasI, gnnbf);
  gemm_qkv<<<dim3(32, 8, 3), 256, 0, stream>>>(nx, wt, bq, bk, bv, qkv);
  gemm_gnnv<<<dim3(8, 8, 4), 256, 0, stream>>>(gnnbf, vt, xvg);
  attn_kernel<<<dim3(8, 16, 4), 256, 0, stream>>>(
      qkv, qkv + (size_t)4 * MB, vt, biasI, xvg, xvbuf);
  gemm_wo<<<dim3(32, 8), 256, 0, stream>>>(xvbuf, wt + (size_t)3 * MB, bo, x, x1);
  ln_kernel<<<4096, 256, 0, stream>>>(x1, g2, b2, hbuf);
  for (int half = 0; half < 2; ++half) {
    const u16* hh = hbuf + (size_t)half * 2048 * 1024;
    gemm_w1<<<dim3(16, 32), 256, 0, stream>>>(hh, wt + (size_t)4 * MB, bf1, ff1h);
    gemm_w2<<<dim3(16, 8), 256, 0, stream>>>(
        ff1h, wt + (size_t)8 * MB, bf2, x1 + (size_t)half * 2048 * 1024,
        out + (size_t)half * 2048 * 1024);
  }
}

// Round 4
// 313.378 us; speedup vs baseline: 1.2926x; 1.2926x over previous
//
#include <hip/hip_runtime.h>
#include <hip/hip_bf16.h>

typedef unsigned short u16;
typedef short bf16x8 __attribute__((ext_vector_type(8)));
typedef float f32x4 __attribute__((ext_vector_type(4)));

#define B_ 4
#define S_ 1024
#define E_ 1024
#define H_ 16
#define FF_ 4096
#define D_ 64
#define M_ 4096  /* B*S */

__device__ __forceinline__ u16 f2bf(float f) {
  unsigned int u = __builtin_bit_cast(unsigned int, f);
  u += 0x7fffu + ((u >> 16) & 1u);   // RNE
  return (u16)(u >> 16);
}
__device__ __forceinline__ float bf2f(u16 v) {
  unsigned int u = ((unsigned int)v) << 16;
  return __builtin_bit_cast(float, u);
}

__device__ __forceinline__ void gld_lds16(const void* g, void* l) {
  __builtin_amdgcn_global_load_lds((__attribute__((address_space(1))) void*)g,
                                   (__attribute__((address_space(3))) void*)l,
                                   16, 0, 0);
}

// ---------------------------------------------------------------------------
// Weight cast+transpose: W (K x N fp32) -> Wt (N x K bf16), all 6 weights
// ---------------------------------------------------------------------------
__global__ void __launch_bounds__(256) cast_transpose_all(
    const float* __restrict__ wq, const float* __restrict__ wk,
    const float* __restrict__ wv, const float* __restrict__ wo,
    const float* __restrict__ w1, const float* __restrict__ w2,
    u16* __restrict__ wt) {
  int bid = blockIdx.x;
  const float* src; u16* dst; int K, N; int local;
  if (bid < 4096) {
    int wsel = bid >> 10; local = bid & 1023; K = 1024; N = 1024;
    src = wsel == 0 ? wq : wsel == 1 ? wk : wsel == 2 ? wv : wo;
    dst = wt + (size_t)wsel * 1024 * 1024;
  } else if (bid < 8192) {
    local = bid - 4096; K = 1024; N = 4096; src = w1;
    dst = wt + (size_t)4 * 1024 * 1024;
  } else {
    local = bid - 8192; K = 4096; N = 1024; src = w2;
    dst = wt + (size_t)8 * 1024 * 1024;
  }
  int tiles_n = N >> 5;
  int n0 = (local % tiles_n) << 5, k0 = (local / tiles_n) << 5;
  __shared__ float tl[32][33];
  int tx = threadIdx.x & 31, ty = threadIdx.x >> 5;
#pragma unroll
  for (int i = 0; i < 4; ++i)
    tl[ty + i * 8][tx] = src[(size_t)(k0 + ty + i * 8) * N + n0 + tx];
  __syncthreads();
#pragma unroll
  for (int i = 0; i < 4; ++i)
    dst[(size_t)(n0 + ty + i * 8) * K + k0 + tx] = f2bf(tl[tx][ty + i * 8]);
}

// ---------------------------------------------------------------------------
// mask -> additive interleaved bias (coalesced ushort4 writes); gnn -> bf16
// biasI[((b*16+kt)*1024+q)*64 + c*4+f] = mask[b][q][kt*64+f*16+c]==0 ? -30000:0
// ---------------------------------------------------------------------------
__global__ void __launch_bounds__(256) cast_maskgnn(
    const float* __restrict__ mask, const float* __restrict__ gnn,
    u16* __restrict__ biasI, u16* __restrict__ gnnbf) {
  int row = blockIdx.x;             // b*1024 + q
  int b = row >> 10, q = row & 1023;
  int t = threadIdx.x;
  __shared__ float mrow[1024];
  const float* mp = mask + ((size_t)row << 10);
  const float* gp = gnn + ((size_t)row << 10);
  float4 mv = *(const float4*)(mp + t * 4);
  *(float4*)(mrow + t * 4) = mv;
  float4 gv = *(const float4*)(gp + t * 4);
  ushort4 g4;
  g4.x = f2bf(gv.x); g4.y = f2bf(gv.y); g4.z = f2bf(gv.z); g4.w = f2bf(gv.w);
  *(ushort4*)(gnnbf + ((size_t)row << 10) + t * 4) = g4;
  __syncthreads();
  int kt = t >> 4, c = t & 15;
  const u16 NEG = f2bf(-30000.f);
  ushort4 o;
  o.x = (mrow[kt * 64 + c] == 0.f) ? NEG : (u16)0;
  o.y = (mrow[kt * 64 + 16 + c] == 0.f) ? NEG : (u16)0;
  o.z = (mrow[kt * 64 + 32 + c] == 0.f) ? NEG : (u16)0;
  o.w = (mrow[kt * 64 + 48 + c] == 0.f) ? NEG : (u16)0;
  *(ushort4*)(biasI + (((size_t)(b * 16 + kt) << 10) + q) * 64 + c * 4) = o;
}

// ---------------------------------------------------------------------------
// V (b,h,s,d) -> Vt (b, h*64+d, s)  — LDS-tiled transpose, coalesced both ways
// ---------------------------------------------------------------------------
__global__ void __launch_bounds__(256) vtrans_kernel(
    const u16* __restrict__ v, u16* __restrict__ vt) {
  int st = blockIdx.x, h = blockIdx.y, b = blockIdx.z;
  __shared__ u16 tl[64][72];
  const u16* src = v + ((((size_t)(b * 16 + h)) << 10) + (st << 6)) * 64;
  int r = threadIdx.x >> 2, g = (threadIdx.x & 3) << 4;
  *(uint4*)&tl[r][g] = *(const uint4*)(src + r * 64 + g);
  *(uint4*)&tl[r][g + 8] = *(const uint4*)(src + r * 64 + g + 8);
  __syncthreads();
  u16 tmp[16];
#pragma unroll
  for (int i = 0; i < 16; ++i) tmp[i] = tl[g + i][r];
  u16* dst = vt + ((size_t)b << 20) + (((size_t)(h * 64 + r)) << 10) + (st << 6) + g;
  *(uint4*)(dst) = *(uint4*)(tmp);
  *(uint4*)(dst + 8) = *(uint4*)(tmp + 8);
}

// ---------------------------------------------------------------------------
// LayerNorm: fp32 (M x 1024) -> bf16. One block per row.
// ---------------------------------------------------------------------------
__global__ void __launch_bounds__(256) ln_kernel(
    const float* __restrict__ x, const float* __restrict__ g,
    const float* __restrict__ bt, u16* __restrict__ out) {
  int row = blockIdx.x, t = threadIdx.x;
  const float* xr = x + (size_t)row * 1024;
  float4 v = *(const float4*)(xr + t * 4);
  float s = v.x + v.y + v.z + v.w;
  float q = v.x * v.x + v.y * v.y + v.z * v.z + v.w * v.w;
#pragma unroll
  for (int off = 1; off < 64; off <<= 1) {
    s += __shfl_xor(s, off);
    q += __shfl_xor(q, off);
  }
  __shared__ float sb[4], qb[4];
  int w = t >> 6, l = t & 63;
  if (l == 0) { sb[w] = s; qb[w] = q; }
  __syncthreads();
  s = sb[0] + sb[1] + sb[2] + sb[3];
  q = qb[0] + qb[1] + qb[2] + qb[3];
  float mean = s * (1.f / 1024.f);
  float var = q * (1.f / 1024.f) - mean * mean;
  float rs = rsqrtf(var + 1e-5f);
  float4 gv = *(const float4*)(g + t * 4);
  float4 bv = *(const float4*)(bt + t * 4);
  ushort4 o;
  o.x = f2bf((v.x - mean) * rs * gv.x + bv.x);
  o.y = f2bf((v.y - mean) * rs * gv.y + bv.y);
  o.z = f2bf((v.z - mean) * rs * gv.z + bv.z);
  o.w = f2bf((v.w - mean) * rs * gv.w + bv.w);
  *(ushort4*)(out + (size_t)row * 1024 + t * 4) = o;
}

// ---------------------------------------------------------------------------
// GEMM core 128x128, BK=64: C = A(MxK) @ Bt(NxK)^T, bf16 in fp32 acc
// ---------------------------------------------------------------------------
__device__ __forceinline__ void gemm_core_128(
    const u16* __restrict__ A, const u16* __restrict__ Bt, int Kdim,
    int bm, int bn, u16* ldsA, u16* ldsB, f32x4 acc[4][4]) {
  const int tid = threadIdx.x;
  const int w = tid >> 6, l = tid & 63;
  const int wm = (w >> 1) << 6, wn = (w & 1) << 6;
  const int lrow = l >> 3;
  const int cg = (l & 7) ^ lrow;
  const size_t arow0 = (size_t)(bm << 7) * Kdim;
  const size_t brow0 = (size_t)(bn << 7) * Kdim;
  for (int kt = 0; kt < Kdim; kt += 64) {
#pragma unroll
    for (int i = 0; i < 4; ++i) {
      int c = (w << 2) + i;
      int row = (c << 3) + lrow;
      gld_lds16(A + arow0 + (size_t)row * Kdim + kt + (cg << 3), ldsA + (c << 9));
      gld_lds16(Bt + brow0 + (size_t)row * Kdim + kt + (cg << 3), ldsB + (c << 9));
    }
    __syncthreads();
    bf16x8 af[2][4], bfr[2][4];
    const int rr = l & 15;
    const int kgb = l >> 4;
#pragma unroll
    for (int ks = 0; ks < 2; ++ks) {
      const int kg = kgb + (ks << 2);
#pragma unroll
      for (int f = 0; f < 4; ++f) {
        int ra = wm + (f << 4) + rr;
        af[ks][f] = *(const bf16x8*)(ldsA + (ra << 6) + ((kg ^ (ra & 7)) << 3));
        int rb = wn + (f << 4) + rr;
        bfr[ks][f] = *(const bf16x8*)(ldsB + (rb << 6) + ((kg ^ (rb & 7)) << 3));
      }
    }
#pragma unroll
    for (int fm = 0; fm < 4; ++fm)
#pragma unroll
      for (int fn = 0; fn < 4; ++fn)
#pragma unroll
        for (int ks = 0; ks < 2; ++ks)
          acc[fm][fn] = __builtin_amdgcn_mfma_f32_16x16x32_bf16(
              af[ks][fm], bfr[ks][fn], acc[fm][fn], 0, 0, 0);
    __syncthreads();
  }
}

#define ACC_INIT()                        \
  f32x4 acc[4][4];                        \
  { f32x4 zf = {0.f, 0.f, 0.f, 0.f};      \
_Pragma("unroll")                         \
    for (int a = 0; a < 4; ++a)           \
_Pragma("unroll")                         \
      for (int bb = 0; bb < 4; ++bb) acc[a][bb] = zf; }

#define EPI_SETUP()                                     \
  const int w = threadIdx.x >> 6, l = threadIdx.x & 63; \
  const int wm = (w >> 1) << 6, wn = (w & 1) << 6;

// --- QKV: all z write (b,h,s,d); z=2 -> vtmp ---------------------------------
__global__ void __launch_bounds__(256) gemm_qkv(
    const u16* __restrict__ nx, const u16* __restrict__ wt,
    const float* __restrict__ bq, const float* __restrict__ bk,
    const float* __restrict__ bv, u16* __restrict__ qk, u16* __restrict__ vtmp) {
  __shared__ __attribute__((aligned(16))) u16 lds[2 * 128 * 64];
  ACC_INIT();
  int z = blockIdx.z;
  const u16* Bt = wt + (size_t)z * 1024 * 1024;
  const float* bias = z == 0 ? bq : z == 1 ? bk : bv;
  u16* out = z == 2 ? vtmp : qk + (size_t)z * M_ * 1024;
  gemm_core_128(nx, Bt, 1024, blockIdx.x, blockIdx.y, lds, lds + 128 * 64, acc);
  EPI_SETUP();
#pragma unroll
  for (int fm = 0; fm < 4; ++fm)
#pragma unroll
    for (int fn = 0; fn < 4; ++fn)
#pragma unroll
      for (int j = 0; j < 4; ++j) {
        int row = (blockIdx.x << 7) + wm + (fm << 4) + ((l >> 4) << 2) + j;
        int col = (blockIdx.y << 7) + wn + (fn << 4) + (l & 15);
        float v = acc[fm][fn][j] + bias[col];
        int b = row >> 10, s = row & 1023;
        int h = col >> 6, d = col & 63;
        out[(((size_t)(b * 16 + h) << 10) + s) * 64 + d] = f2bf(v);
      }
}

// --- gnnV: xvg[b,q,e] = gnnbf[b] @ Vt[b]^T (bf16 out) ------------------------
__global__ void __launch_bounds__(256) gemm_gnnv(
    const u16* __restrict__ gnnbf, const u16* __restrict__ vt,
    u16* __restrict__ xvg) {
  __shared__ __attribute__((aligned(16))) u16 lds[2 * 128 * 64];
  ACC_INIT();
  int b = blockIdx.z;
  const u16* A = gnnbf + ((size_t)b << 20);
  const u16* Bt = vt + ((size_t)b << 20);
  u16* out = xvg + ((size_t)b << 20);
  gemm_core_128(A, Bt, 1024, blockIdx.x, blockIdx.y, lds, lds + 128 * 64, acc);
  EPI_SETUP();
#pragma unroll
  for (int fm = 0; fm < 4; ++fm)
#pragma unroll
    for (int fn = 0; fn < 4; ++fn)
#pragma unroll
      for (int j = 0; j < 4; ++j) {
        int row = (blockIdx.x << 7) + wm + (fm << 4) + ((l >> 4) << 2) + j;
        int col = (blockIdx.y << 7) + wn + (fn << 4) + (l & 15);
        out[((size_t)row << 10) + col] = f2bf(acc[fm][fn][j]);
      }
}

// --- Wo: x1 = x + xv@Wo + bo (fp32 out) --------------------------------------
__global__ void __launch_bounds__(256) gemm_wo(
    const u16* __restrict__ xv, const u16* __restrict__ wt,
    const float* __restrict__ bo, const float* __restrict__ xres,
    float* __restrict__ x1) {
  __shared__ __attribute__((aligned(16))) u16 lds[2 * 128 * 64];
  ACC_INIT();
  gemm_core_128(xv, wt, 1024, blockIdx.x, blockIdx.y, lds, lds + 128 * 64, acc);
  EPI_SETUP();
#pragma unroll
  for (int fm = 0; fm < 4; ++fm)
#pragma unroll
    for (int fn = 0; fn < 4; ++fn)
#pragma unroll
      for (int j = 0; j < 4; ++j) {
        int row = (blockIdx.x << 7) + wm + (fm << 4) + ((l >> 4) << 2) + j;
        int col = (blockIdx.y << 7) + wn + (fn << 4) + (l & 15);
        size_t idx = ((size_t)row << 10) + col;
        x1[idx] = acc[fm][fn][j] + bo[col] + xres[idx];
      }
}

// --- W1: ff1 = gelu(h@W1 + bf1) bf16 (M x FF) --------------------------------
__global__ void __launch_bounds__(256) gemm_w1(
    const u16* __restrict__ hb, const u16* __restrict__ wt,
    const float* __restrict__ bf1, u16* __restrict__ ff1) {
  __shared__ __attribute__((aligned(16))) u16 lds[2 * 128 * 64];
  ACC_INIT();
  gemm_core_128(hb, wt, 1024, blockIdx.x, blockIdx.y, lds, lds + 128 * 64, acc);
  EPI_SETUP();
#pragma unroll
  for (int fm = 0; fm < 4; ++fm)
#pragma unroll
    for (int fn = 0; fn < 4; ++fn)
#pragma unroll
      for (int j = 0; j < 4; ++j) {
        int row = (blockIdx.x << 7) + wm + (fm << 4) + ((l >> 4) << 2) + j;
        int col = (blockIdx.y << 7) + wn + (fn << 4) + (l & 15);
        float v = acc[fm][fn][j] + bf1[col];
        float ge = 0.5f * v * (1.f + erff(v * 0.70710678118654752f));
        ff1[((size_t)row << 12) + col] = f2bf(ge);
      }
}

// --- W2: out = x1 + ff1@W2 + bf2 (fp32, K=4096) ------------------------------
__global__ void __launch_bounds__(256) gemm_w2(
    const u16* __restrict__ ff1, const u16* __restrict__ wt,
    const float* __restrict__ bf2, const float* __restrict__ x1,
    float* __restrict__ out) {
  __shared__ __attribute__((aligned(16))) u16 lds[2 * 128 * 64];
  ACC_INIT();
  gemm_core_128(ff1, wt, 4096, blockIdx.x, blockIdx.y, lds, lds + 128 * 64, acc);
  EPI_SETUP();
#pragma unroll
  for (int fm = 0; fm < 4; ++fm)
#pragma unroll
    for (int fn = 0; fn < 4; ++fn)
#pragma unroll
      for (int j = 0; j < 4; ++j) {
        int row = (blockIdx.x << 7) + wm + (fm << 4) + ((l >> 4) << 2) + j;
        int col = (blockIdx.y << 7) + wn + (fn << 4) + (l & 15);
        size_t idx = ((size_t)row << 10) + col;
        out[idx] = acc[fm][fn][j] + bf2[col] + x1[idx];
      }
}

// ---------------------------------------------------------------------------
// Flash attention: grid (8 qt, 16 h, 4 b); 4 waves x 32 q-rows; KV tile 64.
// exp2-domain scores; group running-max (4 shuffles/iter); row-sum via
// ones-column MFMA. Output adds precomputed gnn@V.
// ---------------------------------------------------------------------------
__global__ void __launch_bounds__(256, 2) attn_kernel(
    const u16* __restrict__ Q, const u16* __restrict__ K,
    const u16* __restrict__ Vt, const u16* __restrict__ biasI,
    const u16* __restrict__ xvg, u16* __restrict__ xv) {
  const int qt = blockIdx.x, h = blockIdx.y, b = blockIdx.z;
  const int tid = threadIdx.x, w = tid >> 6, l = tid & 63;
  __shared__ __attribute__((aligned(16))) u16 kbuf[2][64 * 64];
  __shared__ __attribute__((aligned(16))) u16 vbuf[2][64 * 64];
  __shared__ __attribute__((aligned(16))) u16 pbuf[4][32 * 64];
  const size_t bh = ((size_t)(b * 16 + h)) << 16;
  const u16* Qb = Q + bh;
  const u16* Kb = K + bh;
  const u16* Vtb = Vt + ((size_t)b << 20) + ((size_t)(h * 64) << 10);
  const u16* biasb = biasI + ((size_t)b << 20);
  const int q0 = (qt << 7) + (w << 5);
  const int lrow = l >> 3, cg = (l & 7) ^ lrow;
  const int l4 = l >> 4, lo = l & 15;
  u16* p_w = pbuf[w];
  const float SC = 0.125f * 1.44269504f;   // exp2 domain

  bf16x8 qf[2][2];
#pragma unroll
  for (int m = 0; m < 2; ++m)
#pragma unroll
    for (int ks = 0; ks < 2; ++ks)
      qf[m][ks] = *(const bf16x8*)(Qb + ((size_t)(q0 + m * 16 + lo) << 6) +
                                   l4 * 8 + ks * 32);
  bf16x8 onesf;
#pragma unroll
  for (int j = 0; j < 8; ++j) onesf[j] = (short)0x3F80;

  float run_m = -1e30f;
  f32x4 osoft[2][4], osum[2];
  f32x4 zf = {0.f, 0.f, 0.f, 0.f};
#pragma unroll
  for (int m = 0; m < 2; ++m) {
    osum[m] = zf;
#pragma unroll
    for (int fd = 0; fd < 4; ++fd) osoft[m][fd] = zf;
  }

#define STAGE(T, BUF)                                                          \
  {                                                                            \
    int kv0s = (T) << 6;                                                       \
    u16* kd = &kbuf[BUF][0];                                                   \
    u16* vd = &vbuf[BUF][0];                                                   \
    _Pragma("unroll") for (int i = 0; i < 2; ++i) {                            \
      int c = (w << 1) + i;                                                    \
      gld_lds16(Kb + ((size_t)(kv0s + (c << 3) + lrow) << 6) + (cg << 3),      \
                kd + (c << 9));                                                \
      gld_lds16(Vtb + ((size_t)((c << 3) + lrow) << 10) + kv0s + (cg << 3),    \
                vd + (c << 9));                                                \
    }                                                                          \
  }

  STAGE(0, 0);
  __syncthreads();

  for (int t = 0; t < 16; ++t) {
    const int cur = t & 1;
    if (t < 15) STAGE(t + 1, cur ^ 1);
    const u16* kb_ = &kbuf[cur][0];
    const u16* vb_ = &vbuf[cur][0];
    ushort4 bv4[2][4];
#pragma unroll
    for (int m = 0; m < 2; ++m)
#pragma unroll
      for (int j = 0; j < 4; ++j)
        bv4[m][j] = *(const ushort4*)(
            biasb + (((size_t)(t * 1024 + q0 + m * 16 + l4 * 4 + j)) << 6) +
            lo * 4);
    // QK^T
    f32x4 sacc[2][4];
#pragma unroll
    for (int m = 0; m < 2; ++m)
#pragma unroll
      for (int fn = 0; fn < 4; ++fn) sacc[m][fn] = zf;
#pragma unroll
    for (int ks = 0; ks < 2; ++ks) {
      const int kg = l4 + (ks << 2);
      bf16x8 kf[4];
#pragma unroll
      for (int fn = 0; fn < 4; ++fn) {
        int rk = (fn << 4) + lo;
        kf[fn] = *(const bf16x8*)(kb_ + (rk << 6) + ((kg ^ (rk & 7)) << 3));
      }
#pragma unroll
      for (int m = 0; m < 2; ++m)
#pragma unroll
        for (int fn = 0; fn < 4; ++fn)
          sacc[m][fn] = __builtin_amdgcn_mfma_f32_16x16x32_bf16(
              qf[m][ks], kf[fn], sacc[m][fn], 0, 0, 0);
    }
    // scores (exp2 domain) + group max
    float tm = -1e30f;
#pragma unroll
    for (int m = 0; m < 2; ++m)
#pragma unroll
      for (int j = 0; j < 4; ++j) {
        u16 bb[4] = {bv4[m][j].x, bv4[m][j].y, bv4[m][j].z, bv4[m][j].w};
#pragma unroll
        for (int fn = 0; fn < 4; ++fn) {
          float s = sacc[m][fn][j] * SC + bf2f(bb[fn]);
          sacc[m][fn][j] = s;
          tm = fmaxf(tm, s);
        }
      }
#pragma unroll
    for (int off = 1; off < 16; off <<= 1) tm = fmaxf(tm, __shfl_xor(tm, off));
    float nm = fmaxf(fmaxf(run_m, tm), -10000.f);
    float scale = exp2f(run_m - nm);
    run_m = nm;
    // P = exp2(s - nm) -> bf16 LDS (per-wave region); rescale accumulators
#pragma unroll
    for (int m = 0; m < 2; ++m) {
#pragma unroll
      for (int fn = 0; fn < 4; ++fn)
#pragma unroll
        for (int j = 0; j < 4; ++j) {
          float p = exp2f(sacc[m][fn][j] - nm);
          int prow = (m << 4) + (l4 << 2) + j;
          int pcol = (fn << 4) + lo;
          p_w[(prow << 6) + (pcol ^ ((prow & 7) << 3))] = f2bf(p);
        }
      osum[m] *= scale;
#pragma unroll
      for (int fd = 0; fd < 4; ++fd) osoft[m][fd] *= scale;
    }
    // PV + ones-column rowsum
#pragma unroll
    for (int ks = 0; ks < 2; ++ks) {
      const int kg = l4 + (ks << 2);
      bf16x8 pf[2], vf[4];
#pragma unroll
      for (int m = 0; m < 2; ++m) {
        int pr = (m << 4) + lo;
        pf[m] = *(const bf16x8*)(p_w + (pr << 6) + ((kg ^ (pr & 7)) << 3));
      }
#pragma unroll
      for (int fd = 0; fd < 4; ++fd) {
        int rd = (fd << 4) + lo;
        vf[fd] = *(const bf16x8*)(vb_ + (rd << 6) + ((kg ^ (rd & 7)) << 3));
      }
#pragma unroll
      for (int m = 0; m < 2; ++m) {
        osum[m] = __builtin_amdgcn_mfma_f32_16x16x32_bf16(
            pf[m], onesf, osum[m], 0, 0, 0);
#pragma unroll
        for (int fd = 0; fd < 4; ++fd)
          osoft[m][fd] = __builtin_amdgcn_mfma_f32_16x16x32_bf16(
              pf[m], vf[fd], osoft[m][fd], 0, 0, 0);
      }
    }
    __syncthreads();
  }
  // epilogue
#pragma unroll
  for (int m = 0; m < 2; ++m)
#pragma unroll
    for (int fd = 0; fd < 4; ++fd)
#pragma unroll
      for (int j = 0; j < 4; ++j) {
        int qrow = q0 + (m << 4) + (l4 << 2) + j;
        int e = (h << 6) + (fd << 4) + lo;
        size_t idx = (((size_t)(b * 1024 + qrow)) << 10) + e;
        float o = osoft[m][fd][j] / osum[m][j] + bf2f(xvg[idx]);
        xv[idx] = f2bf(o);
      }
#undef STAGE
}

// ---------------------------------------------------------------------------
extern "C" void kernel_launch(void* const* d_in, const int* in_sizes, int n_in,
                              void* d_out, int out_size, void* d_ws, size_t ws_size,
                              hipStream_t stream) {
  (void)in_sizes; (void)n_in; (void)out_size; (void)ws_size;
  const float* x   = (const float*)d_in[0];
  const float* mask= (const float*)d_in[1];
  const float* gnn = (const float*)d_in[2];
  const float* Wq  = (const float*)d_in[3];
  const float* bq  = (const float*)d_in[4];
  const float* Wk  = (const float*)d_in[5];
  const float* bk  = (const float*)d_in[6];
  const float* Wv  = (const float*)d_in[7];
  const float* bv  = (const float*)d_in[8];
  const float* Wo  = (const float*)d_in[9];
  const float* bo  = (const float*)d_in[10];
  const float* g1  = (const float*)d_in[11];
  const float* b1  = (const float*)d_in[12];
  const float* g2  = (const float*)d_in[13];
  const float* b2  = (const float*)d_in[14];
  const float* W1  = (const float*)d_in[15];
  const float* bf1 = (const float*)d_in[16];
  const float* W2  = (const float*)d_in[17];
  const float* bf2 = (const float*)d_in[18];
  float* out = (float*)d_out;

  char* ws = (char*)d_ws;
  const size_t MB = 1024 * 1024;
  // layout (MB): 0-24 wt | 24-32 nx -> xv -> hbuf | 32-40 Q | 40-48 K
  // | 48-56 Vt | 56-64 biasI | 64-72 gnnbf | 72-80 vtmp -> xvg
  // post-attn: x1 fp32 64-80 | ff1 32-64
  u16*  wt    = (u16*)(ws);
  u16*  nx    = (u16*)(ws + 24 * MB);
  u16*  xvbuf = (u16*)(ws + 24 * MB);
  u16*  hbuf  = (u16*)(ws + 24 * MB);
  u16*  qk    = (u16*)(ws + 32 * MB);
  u16*  vt    = (u16*)(ws + 48 * MB);
  u16*  biasI = (u16*)(ws + 56 * MB);
  u16*  gnnbf = (u16*)(ws + 64 * MB);
  u16*  vtmp  = (u16*)(ws + 72 * MB);
  u16*  xvg   = (u16*)(ws + 72 * MB);
  float* x1   = (float*)(ws + 64 * MB);
  u16*  ff1   = (u16*)(ws + 32 * MB);

  cast_transpose_all<<<12288, 256, 0, stream>>>(Wq, Wk, Wv, Wo, W1, W2, wt);
  ln_kernel<<<4096, 256, 0, stream>>>(x, g1, b1, nx);
  cast_maskgnn<<<4096, 256, 0, stream>>>(mask, gnn, biasI, gnnbf);
  gemm_qkv<<<dim3(32, 8, 3), 256, 0, stream>>>(nx, wt, bq, bk, bv, qk, vtmp);
  vtrans_kernel<<<dim3(16, 16, 4), 256, 0, stream>>>(vtmp, vt);
  gemm_gnnv<<<dim3(8, 8, 4), 256, 0, stream>>>(gnnbf, vt, xvg);
  attn_kernel<<<dim3(8, 16, 4), 256, 0, stream>>>(
      qk, qk + (size_t)4 * MB, vt, biasI, xvg, xvbuf);
  gemm_wo<<<dim3(32, 8), 256, 0, stream>>>(xvbuf, wt + (size_t)3 * MB, bo, x, x1);
  ln_kernel<<<4096, 256, 0, stream>>>(x1, g2, b2, hbuf);
  gemm_w1<<<dim3(32, 32), 256, 0, stream>>>(hbuf, wt + (size_t)4 * MB, bf1, ff1);
  gemm_w2<<<dim3(32, 8), 256, 0, stream>>>(ff1, wt + (size_t)8 * MB, bf2, x1, out);
}

// Round 5
// 258.220 us; speedup vs baseline: 1.5688x; 1.2136x over previous
//
#include <hip/hip_runtime.h>
#include <hip/hip_bf16.h>

typedef unsigned short u16;
typedef short bf16x8 __attribute__((ext_vector_type(8)));
typedef float f32x4 __attribute__((ext_vector_type(4)));

#define B_ 4
#define S_ 1024
#define E_ 1024
#define H_ 16
#define FF_ 4096
#define D_ 64
#define M_ 4096  /* B*S */

__device__ __forceinline__ u16 f2bf(float f) {
  unsigned int u = __builtin_bit_cast(unsigned int, f);
  u += 0x7fffu + ((u >> 16) & 1u);   // RNE
  return (u16)(u >> 16);
}
__device__ __forceinline__ float bf2f(u16 v) {
  unsigned int u = ((unsigned int)v) << 16;
  return __builtin_bit_cast(float, u);
}

__device__ __forceinline__ void gld_lds16(const void* g, void* l) {
  __builtin_amdgcn_global_load_lds((__attribute__((address_space(1))) void*)g,
                                   (__attribute__((address_space(3))) void*)l,
                                   16, 0, 0);
}

// ---------------------------------------------------------------------------
// Weight cast+transpose: W (K x N fp32) -> Wt (N x K bf16), all 6 weights
// ---------------------------------------------------------------------------
__global__ void __launch_bounds__(256) cast_transpose_all(
    const float* __restrict__ wq, const float* __restrict__ wk,
    const float* __restrict__ wv, const float* __restrict__ wo,
    const float* __restrict__ w1, const float* __restrict__ w2,
    u16* __restrict__ wt) {
  int bid = blockIdx.x;
  const float* src; u16* dst; int K, N; int local;
  if (bid < 4096) {
    int wsel = bid >> 10; local = bid & 1023; K = 1024; N = 1024;
    src = wsel == 0 ? wq : wsel == 1 ? wk : wsel == 2 ? wv : wo;
    dst = wt + (size_t)wsel * 1024 * 1024;
  } else if (bid < 8192) {
    local = bid - 4096; K = 1024; N = 4096; src = w1;
    dst = wt + (size_t)4 * 1024 * 1024;
  } else {
    local = bid - 8192; K = 4096; N = 1024; src = w2;
    dst = wt + (size_t)8 * 1024 * 1024;
  }
  int tiles_n = N >> 5;
  int n0 = (local % tiles_n) << 5, k0 = (local / tiles_n) << 5;
  __shared__ float tl[32][33];
  int tx = threadIdx.x & 31, ty = threadIdx.x >> 5;
#pragma unroll
  for (int i = 0; i < 4; ++i)
    tl[ty + i * 8][tx] = src[(size_t)(k0 + ty + i * 8) * N + n0 + tx];
  __syncthreads();
#pragma unroll
  for (int i = 0; i < 4; ++i)
    dst[(size_t)(n0 + ty + i * 8) * K + k0 + tx] = f2bf(tl[tx][ty + i * 8]);
}

// ---------------------------------------------------------------------------
// mask -> additive interleaved bias (coalesced ushort4 writes); gnn -> bf16
// ---------------------------------------------------------------------------
__global__ void __launch_bounds__(256) cast_maskgnn(
    const float* __restrict__ mask, const float* __restrict__ gnn,
    u16* __restrict__ biasI, u16* __restrict__ gnnbf) {
  int row = blockIdx.x;             // b*1024 + q
  int b = row >> 10, q = row & 1023;
  int t = threadIdx.x;
  __shared__ float mrow[1024];
  const float* mp = mask + ((size_t)row << 10);
  const float* gp = gnn + ((size_t)row << 10);
  float4 mv = *(const float4*)(mp + t * 4);
  *(float4*)(mrow + t * 4) = mv;
  float4 gv = *(const float4*)(gp + t * 4);
  ushort4 g4;
  g4.x = f2bf(gv.x); g4.y = f2bf(gv.y); g4.z = f2bf(gv.z); g4.w = f2bf(gv.w);
  *(ushort4*)(gnnbf + ((size_t)row << 10) + t * 4) = g4;
  __syncthreads();
  int kt = t >> 4, c = t & 15;
  const u16 NEG = f2bf(-30000.f);
  ushort4 o;
  o.x = (mrow[kt * 64 + c] == 0.f) ? NEG : (u16)0;
  o.y = (mrow[kt * 64 + 16 + c] == 0.f) ? NEG : (u16)0;
  o.z = (mrow[kt * 64 + 32 + c] == 0.f) ? NEG : (u16)0;
  o.w = (mrow[kt * 64 + 48 + c] == 0.f) ? NEG : (u16)0;
  *(ushort4*)(biasI + (((size_t)(b * 16 + kt) << 10) + q) * 64 + c * 4) = o;
}

// ---------------------------------------------------------------------------
// V (b,h,s,d) -> Vt (b, h*64+d, s)  — LDS-tiled transpose
// ---------------------------------------------------------------------------
__global__ void __launch_bounds__(256) vtrans_kernel(
    const u16* __restrict__ v, u16* __restrict__ vt) {
  int st = blockIdx.x, h = blockIdx.y, b = blockIdx.z;
  __shared__ u16 tl[64][72];
  const u16* src = v + ((((size_t)(b * 16 + h)) << 10) + (st << 6)) * 64;
  int r = threadIdx.x >> 2, g = (threadIdx.x & 3) << 4;
  *(uint4*)&tl[r][g] = *(const uint4*)(src + r * 64 + g);
  *(uint4*)&tl[r][g + 8] = *(const uint4*)(src + r * 64 + g + 8);
  __syncthreads();
  u16 tmp[16];
#pragma unroll
  for (int i = 0; i < 16; ++i) tmp[i] = tl[g + i][r];
  u16* dst = vt + ((size_t)b << 20) + (((size_t)(h * 64 + r)) << 10) + (st << 6) + g;
  *(uint4*)(dst) = *(uint4*)(tmp);
  *(uint4*)(dst + 8) = *(uint4*)(tmp + 8);
}

// ---------------------------------------------------------------------------
// LayerNorm: fp32 (M x 1024) -> bf16. One block per row.
// ---------------------------------------------------------------------------
__global__ void __launch_bounds__(256) ln_kernel(
    const float* __restrict__ x, const float* __restrict__ g,
    const float* __restrict__ bt, u16* __restrict__ out) {
  int row = blockIdx.x, t = threadIdx.x;
  const float* xr = x + (size_t)row * 1024;
  float4 v = *(const float4*)(xr + t * 4);
  float s = v.x + v.y + v.z + v.w;
  float q = v.x * v.x + v.y * v.y + v.z * v.z + v.w * v.w;
#pragma unroll
  for (int off = 1; off < 64; off <<= 1) {
    s += __shfl_xor(s, off);
    q += __shfl_xor(q, off);
  }
  __shared__ float sb[4], qb[4];
  int w = t >> 6, l = t & 63;
  if (l == 0) { sb[w] = s; qb[w] = q; }
  __syncthreads();
  s = sb[0] + sb[1] + sb[2] + sb[3];
  q = qb[0] + qb[1] + qb[2] + qb[3];
  float mean = s * (1.f / 1024.f);
  float var = q * (1.f / 1024.f) - mean * mean;
  float rs = rsqrtf(var + 1e-5f);
  float4 gv = *(const float4*)(g + t * 4);
  float4 bv = *(const float4*)(bt + t * 4);
  ushort4 o;
  o.x = f2bf((v.x - mean) * rs * gv.x + bv.x);
  o.y = f2bf((v.y - mean) * rs * gv.y + bv.y);
  o.z = f2bf((v.z - mean) * rs * gv.z + bv.z);
  o.w = f2bf((v.w - mean) * rs * gv.w + bv.w);
  *(ushort4*)(out + (size_t)row * 1024 + t * 4) = o;
}

// ---------------------------------------------------------------------------
// Double-buffered GEMM core 128x128, BK=64: C = A(M x lda) @ Bt(N x ldb)^T
// STAGE(t+1) issued BEFORE compute(t); one barrier per K-step.
// lds must hold 2*2*8192 u16 (64 KiB).
// ---------------------------------------------------------------------------
__device__ __forceinline__ void gemm_core_db(
    const u16* __restrict__ A, int lda, const u16* __restrict__ Bt, int ldb,
    int nkt, int bm, int bn, u16* lds, f32x4 acc[4][4]) {
  const int tid = threadIdx.x;
  const int w = tid >> 6, l = tid & 63;
  const int wm = (w >> 1) << 6, wn = (w & 1) << 6;
  const int lrow = l >> 3;
  const int cg = (l & 7) ^ lrow;
  const u16* Ab = A + (size_t)(bm << 7) * lda;
  const u16* Bb = Bt + (size_t)(bn << 7) * ldb;
#define GSTAGE(T, BUF)                                                       \
  {                                                                          \
    int kk = (T) << 6;                                                       \
    u16* la = lds + (BUF) * 16384;                                           \
    u16* lb = la + 8192;                                                     \
    _Pragma("unroll") for (int i = 0; i < 4; ++i) {                          \
      int c = (w << 2) + i;                                                  \
      int row = (c << 3) + lrow;                                             \
      gld_lds16(Ab + (size_t)row * lda + kk + (cg << 3), la + (c << 9));     \
      gld_lds16(Bb + (size_t)row * ldb + kk + (cg << 3), lb + (c << 9));     \
    }                                                                        \
  }
  GSTAGE(0, 0);
  __syncthreads();
  for (int t = 0; t < nkt; ++t) {
    if (t + 1 < nkt) GSTAGE(t + 1, (t & 1) ^ 1);
    const u16* la = lds + (t & 1) * 16384;
    const u16* lb = la + 8192;
    bf16x8 af[2][4], bfr[2][4];
    const int rr = l & 15;
    const int kgb = l >> 4;
#pragma unroll
    for (int ks = 0; ks < 2; ++ks) {
      const int kg = kgb + (ks << 2);
#pragma unroll
      for (int f = 0; f < 4; ++f) {
        int ra = wm + (f << 4) + rr;
        af[ks][f] = *(const bf16x8*)(la + (ra << 6) + ((kg ^ (ra & 7)) << 3));
        int rb = wn + (f << 4) + rr;
        bfr[ks][f] = *(const bf16x8*)(lb + (rb << 6) + ((kg ^ (rb & 7)) << 3));
      }
    }
#pragma unroll
    for (int fm = 0; fm < 4; ++fm)
#pragma unroll
      for (int fn = 0; fn < 4; ++fn)
#pragma unroll
        for (int ks = 0; ks < 2; ++ks)
          acc[fm][fn] = __builtin_amdgcn_mfma_f32_16x16x32_bf16(
              af[ks][fm], bfr[ks][fn], acc[fm][fn], 0, 0, 0);
    __syncthreads();
  }
#undef GSTAGE
}

#define ACC_INIT()                        \
  f32x4 acc[4][4];                        \
  { f32x4 zf = {0.f, 0.f, 0.f, 0.f};      \
_Pragma("unroll")                         \
    for (int a = 0; a < 4; ++a)           \
_Pragma("unroll")                         \
      for (int bb = 0; bb < 4; ++bb) acc[a][bb] = zf; }

#define EPI_SETUP()                                     \
  const int w = threadIdx.x >> 6, l = threadIdx.x & 63; \
  const int wm = (w >> 1) << 6, wn = (w & 1) << 6;

#define GEMM_LDS() __shared__ __attribute__((aligned(16))) u16 lds[2 * 2 * 8192]

// --- QKV: all z write (b,h,s,d); z=2 -> vtmp ---------------------------------
__global__ void __launch_bounds__(256, 2) gemm_qkv(
    const u16* __restrict__ nx, const u16* __restrict__ wt,
    const float* __restrict__ bq, const float* __restrict__ bk,
    const float* __restrict__ bv, u16* __restrict__ qk, u16* __restrict__ vtmp) {
  GEMM_LDS();
  ACC_INIT();
  int z = blockIdx.z;
  const u16* Bt = wt + (size_t)z * 1024 * 1024;
  const float* bias = z == 0 ? bq : z == 1 ? bk : bv;
  u16* out = z == 2 ? vtmp : qk + (size_t)z * M_ * 1024;
  gemm_core_db(nx, 1024, Bt, 1024, 16, blockIdx.x, blockIdx.y, lds, acc);
  EPI_SETUP();
#pragma unroll
  for (int fm = 0; fm < 4; ++fm)
#pragma unroll
    for (int fn = 0; fn < 4; ++fn)
#pragma unroll
      for (int j = 0; j < 4; ++j) {
        int row = (blockIdx.x << 7) + wm + (fm << 4) + ((l >> 4) << 2) + j;
        int col = (blockIdx.y << 7) + wn + (fn << 4) + (l & 15);
        float v = acc[fm][fn][j] + bias[col];
        int b = row >> 10, s = row & 1023;
        int h = col >> 6, d = col & 63;
        out[(((size_t)(b * 16 + h) << 10) + s) * 64 + d] = f2bf(v);
      }
}

// --- gnnV: xvg[b,q,e] = gnnbf[b] @ Vt[b]^T (bf16 out) ------------------------
__global__ void __launch_bounds__(256, 2) gemm_gnnv(
    const u16* __restrict__ gnnbf, const u16* __restrict__ vt,
    u16* __restrict__ xvg) {
  GEMM_LDS();
  ACC_INIT();
  int b = blockIdx.z;
  const u16* A = gnnbf + ((size_t)b << 20);
  const u16* Bt = vt + ((size_t)b << 20);
  u16* out = xvg + ((size_t)b << 20);
  gemm_core_db(A, 1024, Bt, 1024, 16, blockIdx.x, blockIdx.y, lds, acc);
  EPI_SETUP();
#pragma unroll
  for (int fm = 0; fm < 4; ++fm)
#pragma unroll
    for (int fn = 0; fn < 4; ++fn)
#pragma unroll
      for (int j = 0; j < 4; ++j) {
        int row = (blockIdx.x << 7) + wm + (fm << 4) + ((l >> 4) << 2) + j;
        int col = (blockIdx.y << 7) + wn + (fn << 4) + (l & 15);
        out[((size_t)row << 10) + col] = f2bf(acc[fm][fn][j]);
      }
}

// --- Wo: x1 = x + xv@Wo + bo (fp32 out) --------------------------------------
__global__ void __launch_bounds__(256, 2) gemm_wo(
    const u16* __restrict__ xv, const u16* __restrict__ wt,
    const float* __restrict__ bo, const float* __restrict__ xres,
    float* __restrict__ x1) {
  GEMM_LDS();
  ACC_INIT();
  gemm_core_db(xv, 1024, wt, 1024, 16, blockIdx.x, blockIdx.y, lds, acc);
  EPI_SETUP();
#pragma unroll
  for (int fm = 0; fm < 4; ++fm)
#pragma unroll
    for (int fn = 0; fn < 4; ++fn)
#pragma unroll
      for (int j = 0; j < 4; ++j) {
        int row = (blockIdx.x << 7) + wm + (fm << 4) + ((l >> 4) << 2) + j;
        int col = (blockIdx.y << 7) + wn + (fn << 4) + (l & 15);
        size_t idx = ((size_t)row << 10) + col;
        x1[idx] = acc[fm][fn][j] + bo[col] + xres[idx];
      }
}

// --- W1: ff1 = gelu(h@W1 + bf1) bf16 (M x FF) --------------------------------
__global__ void __launch_bounds__(256, 2) gemm_w1(
    const u16* __restrict__ hb, const u16* __restrict__ wt,
    const float* __restrict__ bf1, u16* __restrict__ ff1) {
  GEMM_LDS();
  ACC_INIT();
  gemm_core_db(hb, 1024, wt, 1024, 16, blockIdx.x, blockIdx.y, lds, acc);
  EPI_SETUP();
#pragma unroll
  for (int fm = 0; fm < 4; ++fm)
#pragma unroll
    for (int fn = 0; fn < 4; ++fn)
#pragma unroll
      for (int j = 0; j < 4; ++j) {
        int row = (blockIdx.x << 7) + wm + (fm << 4) + ((l >> 4) << 2) + j;
        int col = (blockIdx.y << 7) + wn + (fn << 4) + (l & 15);
        float v = acc[fm][fn][j] + bf1[col];
        float ge = 0.5f * v * (1.f + erff(v * 0.70710678118654752f));
        ff1[((size_t)row << 12) + col] = f2bf(ge);
      }
}

// --- W2: out = x1 + ff1@W2 + bf2 (fp32, K=4096) ------------------------------
__global__ void __launch_bounds__(256, 2) gemm_w2(
    const u16* __restrict__ ff1, const u16* __restrict__ wt,
    const float* __restrict__ bf2, const float* __restrict__ x1,
    float* __restrict__ out) {
  GEMM_LDS();
  ACC_INIT();
  gemm_core_db(ff1, 4096, wt, 4096, 64, blockIdx.x, blockIdx.y, lds, acc);
  EPI_SETUP();
#pragma unroll
  for (int fm = 0; fm < 4; ++fm)
#pragma unroll
    for (int fn = 0; fn < 4; ++fn)
#pragma unroll
      for (int j = 0; j < 4; ++j) {
        int row = (blockIdx.x << 7) + wm + (fm << 4) + ((l >> 4) << 2) + j;
        int col = (blockIdx.y << 7) + wn + (fn << 4) + (l & 15);
        size_t idx = ((size_t)row << 10) + col;
        out[idx] = acc[fm][fn][j] + bf2[col] + x1[idx];
      }
}

// ---------------------------------------------------------------------------
// Flash attention: grid (8 qt, 16 h, 4 b); 4 waves x 32 q-rows; KV tile 64.
// ---------------------------------------------------------------------------
__global__ void __launch_bounds__(256, 2) attn_kernel(
    const u16* __restrict__ Q, const u16* __restrict__ K,
    const u16* __restrict__ Vt, const u16* __restrict__ biasI,
    const u16* __restrict__ xvg, u16* __restrict__ xv) {
  const int qt = blockIdx.x, h = blockIdx.y, b = blockIdx.z;
  const int tid = threadIdx.x, w = tid >> 6, l = tid & 63;
  __shared__ __attribute__((aligned(16))) u16 kbuf[2][64 * 64];
  __shared__ __attribute__((aligned(16))) u16 vbuf[2][64 * 64];
  __shared__ __attribute__((aligned(16))) u16 pbuf[4][32 * 64];
  const size_t bh = ((size_t)(b * 16 + h)) << 16;
  const u16* Qb = Q + bh;
  const u16* Kb = K + bh;
  const u16* Vtb = Vt + ((size_t)b << 20) + ((size_t)(h * 64) << 10);
  const u16* biasb = biasI + ((size_t)b << 20);
  const int q0 = (qt << 7) + (w << 5);
  const int lrow = l >> 3, cg = (l & 7) ^ lrow;
  const int l4 = l >> 4, lo = l & 15;
  u16* p_w = pbuf[w];
  const float SC = 0.125f * 1.44269504f;   // exp2 domain

  bf16x8 qf[2][2];
#pragma unroll
  for (int m = 0; m < 2; ++m)
#pragma unroll
    for (int ks = 0; ks < 2; ++ks)
      qf[m][ks] = *(const bf16x8*)(Qb + ((size_t)(q0 + m * 16 + lo) << 6) +
                                   l4 * 8 + ks * 32);
  bf16x8 onesf;
#pragma unroll
  for (int j = 0; j < 8; ++j) onesf[j] = (short)0x3F80;

  float run_m = -1e30f;
  f32x4 osoft[2][4], osum[2];
  f32x4 zf = {0.f, 0.f, 0.f, 0.f};
#pragma unroll
  for (int m = 0; m < 2; ++m) {
    osum[m] = zf;
#pragma unroll
    for (int fd = 0; fd < 4; ++fd) osoft[m][fd] = zf;
  }

#define STAGE(T, BUF)                                                          \
  {                                                                            \
    int kv0s = (T) << 6;                                                       \
    u16* kd = &kbuf[BUF][0];                                                   \
    u16* vd = &vbuf[BUF][0];                                                   \
    _Pragma("unroll") for (int i = 0; i < 2; ++i) {                            \
      int c = (w << 1) + i;                                                    \
      gld_lds16(Kb + ((size_t)(kv0s + (c << 3) + lrow) << 6) + (cg << 3),      \
                kd + (c << 9));                                                \
      gld_lds16(Vtb + ((size_t)((c << 3) + lrow) << 10) + kv0s + (cg << 3),    \
                vd + (c << 9));                                                \
    }                                                                          \
  }

  STAGE(0, 0);
  __syncthreads();

  for (int t = 0; t < 16; ++t) {
    const int cur = t & 1;
    if (t < 15) STAGE(t + 1, cur ^ 1);
    const u16* kb_ = &kbuf[cur][0];
    const u16* vb_ = &vbuf[cur][0];
    ushort4 bv4[2][4];
#pragma unroll
    for (int m = 0; m < 2; ++m)
#pragma unroll
      for (int j = 0; j < 4; ++j)
        bv4[m][j] = *(const ushort4*)(
            biasb + (((size_t)(t * 1024 + q0 + m * 16 + l4 * 4 + j)) << 6) +
            lo * 4);
    // QK^T
    f32x4 sacc[2][4];
#pragma unroll
    for (int m = 0; m < 2; ++m)
#pragma unroll
      for (int fn = 0; fn < 4; ++fn) sacc[m][fn] = zf;
#pragma unroll
    for (int ks = 0; ks < 2; ++ks) {
      const int kg = l4 + (ks << 2);
      bf16x8 kf[4];
#pragma unroll
      for (int fn = 0; fn < 4; ++fn) {
        int rk = (fn << 4) + lo;
        kf[fn] = *(const bf16x8*)(kb_ + (rk << 6) + ((kg ^ (rk & 7)) << 3));
      }
#pragma unroll
      for (int m = 0; m < 2; ++m)
#pragma unroll
        for (int fn = 0; fn < 4; ++fn)
          sacc[m][fn] = __builtin_amdgcn_mfma_f32_16x16x32_bf16(
              qf[m][ks], kf[fn], sacc[m][fn], 0, 0, 0);
    }
    // scores (exp2 domain) + group max
    float tm = -1e30f;
#pragma unroll
    for (int m = 0; m < 2; ++m)
#pragma unroll
      for (int j = 0; j < 4; ++j) {
        u16 bb[4] = {bv4[m][j].x, bv4[m][j].y, bv4[m][j].z, bv4[m][j].w};
#pragma unroll
        for (int fn = 0; fn < 4; ++fn) {
          float s = sacc[m][fn][j] * SC + bf2f(bb[fn]);
          sacc[m][fn][j] = s;
          tm = fmaxf(tm, s);
        }
      }
#pragma unroll
    for (int off = 1; off < 16; off <<= 1) tm = fmaxf(tm, __shfl_xor(tm, off));
    float nm = fmaxf(fmaxf(run_m, tm), -10000.f);
    float scale = exp2f(run_m - nm);
    run_m = nm;
#pragma unroll
    for (int m = 0; m < 2; ++m) {
#pragma unroll
      for (int fn = 0; fn < 4; ++fn)
#pragma unroll
        for (int j = 0; j < 4; ++j) {
          float p = exp2f(sacc[m][fn][j] - nm);
          int prow = (m << 4) + (l4 << 2) + j;
          int pcol = (fn << 4) + lo;
          p_w[(prow << 6) + (pcol ^ ((prow & 7) << 3))] = f2bf(p);
        }
      osum[m] *= scale;
#pragma unroll
      for (int fd = 0; fd < 4; ++fd) osoft[m][fd] *= scale;
    }
    // PV + ones-column rowsum
#pragma unroll
    for (int ks = 0; ks < 2; ++ks) {
      const int kg = l4 + (ks << 2);
      bf16x8 pf[2], vf[4];
#pragma unroll
      for (int m = 0; m < 2; ++m) {
        int pr = (m << 4) + lo;
        pf[m] = *(const bf16x8*)(p_w + (pr << 6) + ((kg ^ (pr & 7)) << 3));
      }
#pragma unroll
      for (int fd = 0; fd < 4; ++fd) {
        int rd = (fd << 4) + lo;
        vf[fd] = *(const bf16x8*)(vb_ + (rd << 6) + ((kg ^ (rd & 7)) << 3));
      }
#pragma unroll
      for (int m = 0; m < 2; ++m) {
        osum[m] = __builtin_amdgcn_mfma_f32_16x16x32_bf16(
            pf[m], onesf, osum[m], 0, 0, 0);
#pragma unroll
        for (int fd = 0; fd < 4; ++fd)
          osoft[m][fd] = __builtin_amdgcn_mfma_f32_16x16x32_bf16(
              pf[m], vf[fd], osoft[m][fd], 0, 0, 0);
      }
    }
    __syncthreads();
  }
  // epilogue
#pragma unroll
  for (int m = 0; m < 2; ++m)
#pragma unroll
    for (int fd = 0; fd < 4; ++fd)
#pragma unroll
      for (int j = 0; j < 4; ++j) {
        int qrow = q0 + (m << 4) + (l4 << 2) + j;
        int e = (h << 6) + (fd << 4) + lo;
        size_t idx = (((size_t)(b * 1024 + qrow)) << 10) + e;
        float o = osoft[m][fd][j] / osum[m][j] + bf2f(xvg[idx]);
        xv[idx] = f2bf(o);
      }
#undef STAGE
}

// ---------------------------------------------------------------------------
extern "C" void kernel_launch(void* const* d_in, const int* in_sizes, int n_in,
                              void* d_out, int out_size, void* d_ws, size_t ws_size,
                              hipStream_t stream) {
  (void)in_sizes; (void)n_in; (void)out_size; (void)ws_size;
  const float* x   = (const float*)d_in[0];
  const float* mask= (const float*)d_in[1];
  const float* gnn = (const float*)d_in[2];
  const float* Wq  = (const float*)d_in[3];
  const float* bq  = (const float*)d_in[4];
  const float* Wk  = (const float*)d_in[5];
  const float* bk  = (const float*)d_in[6];
  const float* Wv  = (const float*)d_in[7];
  const float* bv  = (const float*)d_in[8];
  const float* Wo  = (const float*)d_in[9];
  const float* bo  = (const float*)d_in[10];
  const float* g1  = (const float*)d_in[11];
  const float* b1  = (const float*)d_in[12];
  const float* g2  = (const float*)d_in[13];
  const float* b2  = (const float*)d_in[14];
  const float* W1  = (const float*)d_in[15];
  const float* bf1 = (const float*)d_in[16];
  const float* W2  = (const float*)d_in[17];
  const float* bf2 = (const float*)d_in[18];
  float* out = (float*)d_out;

  char* ws = (char*)d_ws;
  const size_t MB = 1024 * 1024;
  // layout (MB): 0-24 wt | 24-32 nx -> xv -> hbuf | 32-40 Q | 40-48 K
  // | 48-56 Vt | 56-64 biasI | 64-72 gnnbf | 72-80 vtmp -> xvg
  // post-attn: x1 fp32 64-80 | ff1 32-64
  u16*  wt    = (u16*)(ws);
  u16*  nx    = (u16*)(ws + 24 * MB);
  u16*  xvbuf = (u16*)(ws + 24 * MB);
  u16*  hbuf  = (u16*)(ws + 24 * MB);
  u16*  qk    = (u16*)(ws + 32 * MB);
  u16*  vt    = (u16*)(ws + 48 * MB);
  u16*  biasI = (u16*)(ws + 56 * MB);
  u16*  gnnbf = (u16*)(ws + 64 * MB);
  u16*  vtmp  = (u16*)(ws + 72 * MB);
  u16*  xvg   = (u16*)(ws + 72 * MB);
  float* x1   = (float*)(ws + 64 * MB);
  u16*  ff1   = (u16*)(ws + 32 * MB);

  cast_transpose_all<<<12288, 256, 0, stream>>>(Wq, Wk, Wv, Wo, W1, W2, wt);
  ln_kernel<<<4096, 256, 0, stream>>>(x, g1, b1, nx);
  cast_maskgnn<<<4096, 256, 0, stream>>>(mask, gnn, biasI, gnnbf);
  gemm_qkv<<<dim3(32, 8, 3), 256, 0, stream>>>(nx, wt, bq, bk, bv, qk, vtmp);
  vtrans_kernel<<<dim3(16, 16, 4), 256, 0, stream>>>(vtmp, vt);
  gemm_gnnv<<<dim3(8, 8, 4), 256, 0, stream>>>(gnnbf, vt, xvg);
  attn_kernel<<<dim3(8, 16, 4), 256, 0, stream>>>(
      qk, qk + (size_t)4 * MB, vt, biasI, xvg, xvbuf);
  gemm_wo<<<dim3(32, 8), 256, 0, stream>>>(xvbuf, wt + (size_t)3 * MB, bo, x, x1);
  ln_kernel<<<4096, 256, 0, stream>>>(x1, g2, b2, hbuf);
  gemm_w1<<<dim3(32, 32), 256, 0, stream>>>(hbuf, wt + (size_t)4 * MB, bf1, ff1);
  gemm_w2<<<dim3(32, 8), 256, 0, stream>>>(ff1, wt + (size_t)8 * MB, bf2, x1, out);
}

// Round 6
// 233.574 us; speedup vs baseline: 1.7343x; 1.1055x over previous
//
#include <hip/hip_runtime.h>
#include <hip/hip_bf16.h>

typedef unsigned short u16;
typedef short bf16x8 __attribute__((ext_vector_type(8)));
typedef float f32x4 __attribute__((ext_vector_type(4)));

#define B_ 4
#define S_ 1024
#define E_ 1024
#define H_ 16
#define FF_ 4096
#define D_ 64
#define M_ 4096  /* B*S */

__device__ __forceinline__ u16 f2bf(float f) {
  unsigned int u = __builtin_bit_cast(unsigned int, f);
  u += 0x7fffu + ((u >> 16) & 1u);   // RNE
  return (u16)(u >> 16);
}
__device__ __forceinline__ float bf2f(u16 v) {
  unsigned int u = ((unsigned int)v) << 16;
  return __builtin_bit_cast(float, u);
}

__device__ __forceinline__ void gld_lds16(const void* g, void* l) {
  __builtin_amdgcn_global_load_lds((__attribute__((address_space(1))) void*)g,
                                   (__attribute__((address_space(3))) void*)l,
                                   16, 0, 0);
}

// ---------------------------------------------------------------------------
// Weight cast+transpose: W (K x N fp32) -> Wt (N x K bf16), all 6 weights
// ---------------------------------------------------------------------------
__global__ void __launch_bounds__(256) cast_transpose_all(
    const float* __restrict__ wq, const float* __restrict__ wk,
    const float* __restrict__ wv, const float* __restrict__ wo,
    const float* __restrict__ w1, const float* __restrict__ w2,
    u16* __restrict__ wt) {
  int bid = blockIdx.x;
  const float* src; u16* dst; int K, N; int local;
  if (bid < 4096) {
    int wsel = bid >> 10; local = bid & 1023; K = 1024; N = 1024;
    src = wsel == 0 ? wq : wsel == 1 ? wk : wsel == 2 ? wv : wo;
    dst = wt + (size_t)wsel * 1024 * 1024;
  } else if (bid < 8192) {
    local = bid - 4096; K = 1024; N = 4096; src = w1;
    dst = wt + (size_t)4 * 1024 * 1024;
  } else {
    local = bid - 8192; K = 4096; N = 1024; src = w2;
    dst = wt + (size_t)8 * 1024 * 1024;
  }
  int tiles_n = N >> 5;
  int n0 = (local % tiles_n) << 5, k0 = (local / tiles_n) << 5;
  __shared__ float tl[32][33];
  int tx = threadIdx.x & 31, ty = threadIdx.x >> 5;
#pragma unroll
  for (int i = 0; i < 4; ++i)
    tl[ty + i * 8][tx] = src[(size_t)(k0 + ty + i * 8) * N + n0 + tx];
  __syncthreads();
#pragma unroll
  for (int i = 0; i < 4; ++i)
    dst[(size_t)(n0 + ty + i * 8) * K + k0 + tx] = f2bf(tl[tx][ty + i * 8]);
}

// ---------------------------------------------------------------------------
// mask -> additive C-init bias (exp2 domain, fixed shift C=8): unmasked -> -8,
// masked -> -30008.  Interleaved layout matches MFMA C fragment. gnn -> bf16.
// ---------------------------------------------------------------------------
__global__ void __launch_bounds__(256) cast_maskgnn(
    const float* __restrict__ mask, const float* __restrict__ gnn,
    u16* __restrict__ biasI, u16* __restrict__ gnnbf) {
  int row = blockIdx.x;             // b*1024 + q
  int b = row >> 10, q = row & 1023;
  int t = threadIdx.x;
  __shared__ float mrow[1024];
  const float* mp = mask + ((size_t)row << 10);
  const float* gp = gnn + ((size_t)row << 10);
  float4 mv = *(const float4*)(mp + t * 4);
  *(float4*)(mrow + t * 4) = mv;
  float4 gv = *(const float4*)(gp + t * 4);
  ushort4 g4;
  g4.x = f2bf(gv.x); g4.y = f2bf(gv.y); g4.z = f2bf(gv.z); g4.w = f2bf(gv.w);
  *(ushort4*)(gnnbf + ((size_t)row << 10) + t * 4) = g4;
  __syncthreads();
  int kt = t >> 4, c = t & 15;
  const u16 NEG = f2bf(-30008.f);
  const u16 SHIFT = f2bf(-8.0f);
  ushort4 o;
  o.x = (mrow[kt * 64 + c] == 0.f) ? NEG : SHIFT;
  o.y = (mrow[kt * 64 + 16 + c] == 0.f) ? NEG : SHIFT;
  o.z = (mrow[kt * 64 + 32 + c] == 0.f) ? NEG : SHIFT;
  o.w = (mrow[kt * 64 + 48 + c] == 0.f) ? NEG : SHIFT;
  *(ushort4*)(biasI + (((size_t)(b * 16 + kt) << 10) + q) * 64 + c * 4) = o;
}

// ---------------------------------------------------------------------------
// V (b,h,s,d) -> Vt (b, h*64+d, s)  — LDS-tiled transpose
// ---------------------------------------------------------------------------
__global__ void __launch_bounds__(256) vtrans_kernel(
    const u16* __restrict__ v, u16* __restrict__ vt) {
  int st = blockIdx.x, h = blockIdx.y, b = blockIdx.z;
  __shared__ u16 tl[64][72];
  const u16* src = v + ((((size_t)(b * 16 + h)) << 10) + (st << 6)) * 64;
  int r = threadIdx.x >> 2, g = (threadIdx.x & 3) << 4;
  *(uint4*)&tl[r][g] = *(const uint4*)(src + r * 64 + g);
  *(uint4*)&tl[r][g + 8] = *(const uint4*)(src + r * 64 + g + 8);
  __syncthreads();
  u16 tmp[16];
#pragma unroll
  for (int i = 0; i < 16; ++i) tmp[i] = tl[g + i][r];
  u16* dst = vt + ((size_t)b << 20) + (((size_t)(h * 64 + r)) << 10) + (st << 6) + g;
  *(uint4*)(dst) = *(uint4*)(tmp);
  *(uint4*)(dst + 8) = *(uint4*)(tmp + 8);
}

// ---------------------------------------------------------------------------
// LayerNorm: fp32 (M x 1024) -> bf16. One block per row.
// ---------------------------------------------------------------------------
__global__ void __launch_bounds__(256) ln_kernel(
    const float* __restrict__ x, const float* __restrict__ g,
    const float* __restrict__ bt, u16* __restrict__ out) {
  int row = blockIdx.x, t = threadIdx.x;
  const float* xr = x + (size_t)row * 1024;
  float4 v = *(const float4*)(xr + t * 4);
  float s = v.x + v.y + v.z + v.w;
  float q = v.x * v.x + v.y * v.y + v.z * v.z + v.w * v.w;
#pragma unroll
  for (int off = 1; off < 64; off <<= 1) {
    s += __shfl_xor(s, off);
    q += __shfl_xor(q, off);
  }
  __shared__ float sb[4], qb[4];
  int w = t >> 6, l = t & 63;
  if (l == 0) { sb[w] = s; qb[w] = q; }
  __syncthreads();
  s = sb[0] + sb[1] + sb[2] + sb[3];
  q = qb[0] + qb[1] + qb[2] + qb[3];
  float mean = s * (1.f / 1024.f);
  float var = q * (1.f / 1024.f) - mean * mean;
  float rs = rsqrtf(var + 1e-5f);
  float4 gv = *(const float4*)(g + t * 4);
  float4 bv = *(const float4*)(bt + t * 4);
  ushort4 o;
  o.x = f2bf((v.x - mean) * rs * gv.x + bv.x);
  o.y = f2bf((v.y - mean) * rs * gv.y + bv.y);
  o.z = f2bf((v.z - mean) * rs * gv.z + bv.z);
  o.w = f2bf((v.w - mean) * rs * gv.w + bv.w);
  *(ushort4*)(out + (size_t)row * 1024 + t * 4) = o;
}

// ---------------------------------------------------------------------------
// Double-buffered GEMM core 128x128, BK=64. 64 KiB LDS.
// ---------------------------------------------------------------------------
__device__ __forceinline__ void gemm_core_db(
    const u16* __restrict__ A, int lda, const u16* __restrict__ Bt, int ldb,
    int nkt, int bm, int bn, u16* lds, f32x4 acc[4][4]) {
  const int tid = threadIdx.x;
  const int w = tid >> 6, l = tid & 63;
  const int wm = (w >> 1) << 6, wn = (w & 1) << 6;
  const int lrow = l >> 3;
  const int cg = (l & 7) ^ lrow;
  const u16* Ab = A + (size_t)(bm << 7) * lda;
  const u16* Bb = Bt + (size_t)(bn << 7) * ldb;
#define GSTAGE(T, BUF)                                                       \
  {                                                                          \
    int kk = (T) << 6;                                                       \
    u16* la = lds + (BUF) * 16384;                                           \
    u16* lb = la + 8192;                                                     \
    _Pragma("unroll") for (int i = 0; i < 4; ++i) {                          \
      int c = (w << 2) + i;                                                  \
      int row = (c << 3) + lrow;                                             \
      gld_lds16(Ab + (size_t)row * lda + kk + (cg << 3), la + (c << 9));     \
      gld_lds16(Bb + (size_t)row * ldb + kk + (cg << 3), lb + (c << 9));     \
    }                                                                        \
  }
  GSTAGE(0, 0);
  __syncthreads();
  for (int t = 0; t < nkt; ++t) {
    if (t + 1 < nkt) GSTAGE(t + 1, (t & 1) ^ 1);
    const u16* la = lds + (t & 1) * 16384;
    const u16* lb = la + 8192;
    bf16x8 af[2][4], bfr[2][4];
    const int rr = l & 15;
    const int kgb = l >> 4;
#pragma unroll
    for (int ks = 0; ks < 2; ++ks) {
      const int kg = kgb + (ks << 2);
#pragma unroll
      for (int f = 0; f < 4; ++f) {
        int ra = wm + (f << 4) + rr;
        af[ks][f] = *(const bf16x8*)(la + (ra << 6) + ((kg ^ (ra & 7)) << 3));
        int rb = wn + (f << 4) + rr;
        bfr[ks][f] = *(const bf16x8*)(lb + (rb << 6) + ((kg ^ (rb & 7)) << 3));
      }
    }
#pragma unroll
    for (int fm = 0; fm < 4; ++fm)
#pragma unroll
      for (int fn = 0; fn < 4; ++fn)
#pragma unroll
        for (int ks = 0; ks < 2; ++ks)
          acc[fm][fn] = __builtin_amdgcn_mfma_f32_16x16x32_bf16(
              af[ks][fm], bfr[ks][fn], acc[fm][fn], 0, 0, 0);
    __syncthreads();
  }
#undef GSTAGE
}

// ---------------------------------------------------------------------------
// Double-buffered GEMM core 64x128, BK=64 (2x the blocks for small grids).
// 48 KiB LDS. Waves 1x4: wave w covers all 64 rows x cols [w*32, w*32+32).
// ---------------------------------------------------------------------------
__device__ __forceinline__ void gemm_core_db64(
    const u16* __restrict__ A, int lda, const u16* __restrict__ Bt, int ldb,
    int nkt, int bm, int bn, u16* lds, f32x4 acc[4][2]) {
  const int tid = threadIdx.x;
  const int w = tid >> 6, l = tid & 63;
  const int wn = w << 5;
  const int lrow = l >> 3;
  const int cg = (l & 7) ^ lrow;
  const u16* Ab = A + (size_t)(bm << 6) * lda;
  const u16* Bb = Bt + (size_t)(bn << 7) * ldb;
#define GSTAGE64(T, BUF)                                                     \
  {                                                                          \
    int kk = (T) << 6;                                                       \
    u16* la = lds + (BUF) * 12288;                                           \
    u16* lb = la + 4096;                                                     \
    _Pragma("unroll") for (int i = 0; i < 2; ++i) {                          \
      int c = (w << 1) + i;                                                  \
      int row = (c << 3) + lrow;                                             \
      gld_lds16(Ab + (size_t)row * lda + kk + (cg << 3), la + (c << 9));     \
    }                                                                        \
    _Pragma("unroll") for (int i = 0; i < 4; ++i) {                          \
      int c = (w << 2) + i;                                                  \
      int row = (c << 3) + lrow;                                             \
      gld_lds16(Bb + (size_t)row * ldb + kk + (cg << 3), lb + (c << 9));     \
    }                                                                        \
  }
  GSTAGE64(0, 0);
  __syncthreads();
  for (int t = 0; t < nkt; ++t) {
    if (t + 1 < nkt) GSTAGE64(t + 1, (t & 1) ^ 1);
    const u16* la = lds + (t & 1) * 12288;
    const u16* lb = la + 4096;
    bf16x8 af[2][4], bfr[2][2];
    const int rr = l & 15;
    const int kgb = l >> 4;
#pragma unroll
    for (int ks = 0; ks < 2; ++ks) {
      const int kg = kgb + (ks << 2);
#pragma unroll
      for (int f = 0; f < 4; ++f) {
        int ra = (f << 4) + rr;
        af[ks][f] = *(const bf16x8*)(la + (ra << 6) + ((kg ^ (ra & 7)) << 3));
      }
#pragma unroll
      for (int f = 0; f < 2; ++f) {
        int rb = wn + (f << 4) + rr;
        bfr[ks][f] = *(const bf16x8*)(lb + (rb << 6) + ((kg ^ (rb & 7)) << 3));
      }
    }
#pragma unroll
    for (int fm = 0; fm < 4; ++fm)
#pragma unroll
      for (int fn = 0; fn < 2; ++fn)
#pragma unroll
        for (int ks = 0; ks < 2; ++ks)
          acc[fm][fn] = __builtin_amdgcn_mfma_f32_16x16x32_bf16(
              af[ks][fm], bfr[ks][fn], acc[fm][fn], 0, 0, 0);
    __syncthreads();
  }
#undef GSTAGE64
}

#define ACC_INIT()                        \
  f32x4 acc[4][4];                        \
  { f32x4 zf = {0.f, 0.f, 0.f, 0.f};      \
_Pragma("unroll")                         \
    for (int a = 0; a < 4; ++a)           \
_Pragma("unroll")                         \
      for (int bb = 0; bb < 4; ++bb) acc[a][bb] = zf; }

#define ACC_INIT64()                      \
  f32x4 acc[4][2];                        \
  { f32x4 zf = {0.f, 0.f, 0.f, 0.f};      \
_Pragma("unroll")                         \
    for (int a = 0; a < 4; ++a)           \
_Pragma("unroll")                         \
      for (int bb = 0; bb < 2; ++bb) acc[a][bb] = zf; }

#define EPI_SETUP()                                     \
  const int w = threadIdx.x >> 6, l = threadIdx.x & 63; \
  const int wm = (w >> 1) << 6, wn = (w & 1) << 6;

#define EPI_SETUP64()                                   \
  const int w = threadIdx.x >> 6, l = threadIdx.x & 63; \
  const int wn = w << 5;

#define GEMM_LDS()   __shared__ __attribute__((aligned(16))) u16 lds[2 * 2 * 8192]
#define GEMM_LDS64() __shared__ __attribute__((aligned(16))) u16 lds[2 * 12288]

// --- QKV: all z write (b,h,s,d); z=2 -> vtmp; z=0 (Q) pre-scaled -------------
__global__ void __launch_bounds__(256, 2) gemm_qkv(
    const u16* __restrict__ nx, const u16* __restrict__ wt,
    const float* __restrict__ bq, const float* __restrict__ bk,
    const float* __restrict__ bv, u16* __restrict__ qk, u16* __restrict__ vtmp) {
  GEMM_LDS();
  ACC_INIT();
  int z = blockIdx.z;
  const u16* Bt = wt + (size_t)z * 1024 * 1024;
  const float* bias = z == 0 ? bq : z == 1 ? bk : bv;
  u16* out = z == 2 ? vtmp : qk + (size_t)z * M_ * 1024;
  const float scl = (z == 0) ? 0.18033688f : 1.0f;  // 0.125*log2(e) for Q
  gemm_core_db(nx, 1024, Bt, 1024, 16, blockIdx.x, blockIdx.y, lds, acc);
  EPI_SETUP();
#pragma unroll
  for (int fm = 0; fm < 4; ++fm)
#pragma unroll
    for (int fn = 0; fn < 4; ++fn)
#pragma unroll
      for (int j = 0; j < 4; ++j) {
        int row = (blockIdx.x << 7) + wm + (fm << 4) + ((l >> 4) << 2) + j;
        int col = (blockIdx.y << 7) + wn + (fn << 4) + (l & 15);
        float v = (acc[fm][fn][j] + bias[col]) * scl;
        int b = row >> 10, s = row & 1023;
        int h = col >> 6, d = col & 63;
        out[(((size_t)(b * 16 + h) << 10) + s) * 64 + d] = f2bf(v);
      }
}

// --- gnnV: xvg[b,q,e] = gnnbf[b] @ Vt[b]^T (bf16 out), 64-row tiles ----------
__global__ void __launch_bounds__(256, 2) gemm_gnnv(
    const u16* __restrict__ gnnbf, const u16* __restrict__ vt,
    u16* __restrict__ xvg) {
  GEMM_LDS64();
  ACC_INIT64();
  int b = blockIdx.z;
  const u16* A = gnnbf + ((size_t)b << 20);
  const u16* Bt = vt + ((size_t)b << 20);
  u16* out = xvg + ((size_t)b << 20);
  gemm_core_db64(A, 1024, Bt, 1024, 16, blockIdx.x, blockIdx.y, lds, acc);
  EPI_SETUP64();
#pragma unroll
  for (int fm = 0; fm < 4; ++fm)
#pragma unroll
    for (int fn = 0; fn < 2; ++fn)
#pragma unroll
      for (int j = 0; j < 4; ++j) {
        int row = (blockIdx.x << 6) + (fm << 4) + ((l >> 4) << 2) + j;
        int col = (blockIdx.y << 7) + wn + (fn << 4) + (l & 15);
        out[((size_t)row << 10) + col] = f2bf(acc[fm][fn][j]);
      }
}

// --- Wo: x1 = x + xv@Wo + bo (fp32 out), 64-row tiles ------------------------
__global__ void __launch_bounds__(256, 2) gemm_wo(
    const u16* __restrict__ xv, const u16* __restrict__ wt,
    const float* __restrict__ bo, const float* __restrict__ xres,
    float* __restrict__ x1) {
  GEMM_LDS64();
  ACC_INIT64();
  gemm_core_db64(xv, 1024, wt, 1024, 16, blockIdx.x, blockIdx.y, lds, acc);
  EPI_SETUP64();
#pragma unroll
  for (int fm = 0; fm < 4; ++fm)
#pragma unroll
    for (int fn = 0; fn < 2; ++fn)
#pragma unroll
      for (int j = 0; j < 4; ++j) {
        int row = (blockIdx.x << 6) + (fm << 4) + ((l >> 4) << 2) + j;
        int col = (blockIdx.y << 7) + wn + (fn << 4) + (l & 15);
        size_t idx = ((size_t)row << 10) + col;
        x1[idx] = acc[fm][fn][j] + bo[col] + xres[idx];
      }
}

// --- W1: ff1 = gelu(h@W1 + bf1) bf16 (M x FF) --------------------------------
__global__ void __launch_bounds__(256, 2) gemm_w1(
    const u16* __restrict__ hb, const u16* __restrict__ wt,
    const float* __restrict__ bf1, u16* __restrict__ ff1) {
  GEMM_LDS();
  ACC_INIT();
  gemm_core_db(hb, 1024, wt, 1024, 16, blockIdx.x, blockIdx.y, lds, acc);
  EPI_SETUP();
#pragma unroll
  for (int fm = 0; fm < 4; ++fm)
#pragma unroll
    for (int fn = 0; fn < 4; ++fn)
#pragma unroll
      for (int j = 0; j < 4; ++j) {
        int row = (blockIdx.x << 7) + wm + (fm << 4) + ((l >> 4) << 2) + j;
        int col = (blockIdx.y << 7) + wn + (fn << 4) + (l & 15);
        float v = acc[fm][fn][j] + bf1[col];
        float ge = 0.5f * v * (1.f + erff(v * 0.70710678118654752f));
        ff1[((size_t)row << 12) + col] = f2bf(ge);
      }
}

// --- W2: out = x1 + ff1@W2 + bf2 (fp32, K=4096), 64-row tiles ----------------
__global__ void __launch_bounds__(256, 2) gemm_w2(
    const u16* __restrict__ ff1, const u16* __restrict__ wt,
    const float* __restrict__ bf2, const float* __restrict__ x1,
    float* __restrict__ out) {
  GEMM_LDS64();
  ACC_INIT64();
  gemm_core_db64(ff1, 4096, wt, 4096, 64, blockIdx.x, blockIdx.y, lds, acc);
  EPI_SETUP64();
#pragma unroll
  for (int fm = 0; fm < 4; ++fm)
#pragma unroll
    for (int fn = 0; fn < 2; ++fn)
#pragma unroll
      for (int j = 0; j < 4; ++j) {
        int row = (blockIdx.x << 6) + (fm << 4) + ((l >> 4) << 2) + j;
        int col = (blockIdx.y << 7) + wn + (fn << 4) + (l & 15);
        size_t idx = ((size_t)row << 10) + col;
        out[idx] = acc[fm][fn][j] + bf2[col] + x1[idx];
      }
}

// ---------------------------------------------------------------------------
// Flash attention, fixed-shift softmax (C=8, exp2 domain, shift folded into
// biasI; SC folded into Q). No online max, no cross-lane reduce.
// Grid: 512 blocks (XCD-chunked swizzle); 4 waves x 32 q-rows; KV tile 64.
// ---------------------------------------------------------------------------
__global__ void __launch_bounds__(256, 2) attn_kernel(
    const u16* __restrict__ Q, const u16* __restrict__ K,
    const u16* __restrict__ Vt, const u16* __restrict__ biasI,
    const u16* __restrict__ xvg, u16* __restrict__ xv) {
  const int lin = ((blockIdx.x & 7) << 6) + (blockIdx.x >> 3);  // XCD chunk
  const int qt = lin & 7, h = (lin >> 3) & 15, b = lin >> 7;
  const int tid = threadIdx.x, w = tid >> 6, l = tid & 63;
  __shared__ __attribute__((aligned(16))) u16 kbuf[2][64 * 64];
  __shared__ __attribute__((aligned(16))) u16 vbuf[2][64 * 64];
  __shared__ __attribute__((aligned(16))) u16 pbuf[4][32 * 64];
  const size_t bh = ((size_t)(b * 16 + h)) << 16;
  const u16* Qb = Q + bh;
  const u16* Kb = K + bh;
  const u16* Vtb = Vt + ((size_t)b << 20) + ((size_t)(h * 64) << 10);
  const u16* biasb = biasI + ((size_t)b << 20);
  const int q0 = (qt << 7) + (w << 5);
  const int lrow = l >> 3, cg = (l & 7) ^ lrow;
  const int l4 = l >> 4, lo = l & 15;
  u16* p_w = pbuf[w];

  bf16x8 qf[2][2];
#pragma unroll
  for (int m = 0; m < 2; ++m)
#pragma unroll
    for (int ks = 0; ks < 2; ++ks)
      qf[m][ks] = *(const bf16x8*)(Qb + ((size_t)(q0 + m * 16 + lo) << 6) +
                                   l4 * 8 + ks * 32);
  bf16x8 onesf;
#pragma unroll
  for (int j = 0; j < 8; ++j) onesf[j] = (short)0x3F80;

  f32x4 osoft[2][4], osum[2];
  f32x4 zf = {0.f, 0.f, 0.f, 0.f};
#pragma unroll
  for (int m = 0; m < 2; ++m) {
    osum[m] = zf;
#pragma unroll
    for (int fd = 0; fd < 4; ++fd) osoft[m][fd] = zf;
  }

#define STAGE(T, BUF)                                                          \
  {                                                                            \
    int kv0s = (T) << 6;                                                       \
    u16* kd = &kbuf[BUF][0];                                                   \
    u16* vd = &vbuf[BUF][0];                                                   \
    _Pragma("unroll") for (int i = 0; i < 2; ++i) {                            \
      int c = (w << 1) + i;                                                    \
      gld_lds16(Kb + ((size_t)(kv0s + (c << 3) + lrow) << 6) + (cg << 3),      \
                kd + (c << 9));                                                \
      gld_lds16(Vtb + ((size_t)((c << 3) + lrow) << 10) + kv0s + (cg << 3),    \
                vd + (c << 9));                                                \
    }                                                                          \
  }

  STAGE(0, 0);
  __syncthreads();

  for (int t = 0; t < 16; ++t) {
    const int cur = t & 1;
    if (t < 15) STAGE(t + 1, cur ^ 1);
    const u16* kb_ = &kbuf[cur][0];
    const u16* vb_ = &vbuf[cur][0];
    // C-init from bias (already holds -8 / -30008 in exp2 domain)
    f32x4 sacc[2][4];
#pragma unroll
    for (int m = 0; m < 2; ++m)
#pragma unroll
      for (int j = 0; j < 4; ++j) {
        ushort4 bb = *(const ushort4*)(
            biasb + (((size_t)(t * 1024 + q0 + m * 16 + l4 * 4 + j)) << 6) +
            lo * 4);
        sacc[m][0][j] = bf2f(bb.x);
        sacc[m][1][j] = bf2f(bb.y);
        sacc[m][2][j] = bf2f(bb.z);
        sacc[m][3][j] = bf2f(bb.w);
      }
    // QK^T (scores land directly in exp2 domain, shifted)
    __builtin_amdgcn_s_setprio(1);
#pragma unroll
    for (int ks = 0; ks < 2; ++ks) {
      const int kg = l4 + (ks << 2);
      bf16x8 kf[4];
#pragma unroll
      for (int fn = 0; fn < 4; ++fn) {
        int rk = (fn << 4) + lo;
        kf[fn] = *(const bf16x8*)(kb_ + (rk << 6) + ((kg ^ (rk & 7)) << 3));
      }
#pragma unroll
      for (int m = 0; m < 2; ++m)
#pragma unroll
        for (int fn = 0; fn < 4; ++fn)
          sacc[m][fn] = __builtin_amdgcn_mfma_f32_16x16x32_bf16(
              qf[m][ks], kf[fn], sacc[m][fn], 0, 0, 0);
    }
    __builtin_amdgcn_s_setprio(0);
    // P = exp2(s), half-up pack to bf16, store to per-wave LDS
#pragma unroll
    for (int m = 0; m < 2; ++m)
#pragma unroll
      for (int fn = 0; fn < 4; ++fn)
#pragma unroll
        for (int j = 0; j < 4; ++j) {
          float p = exp2f(sacc[m][fn][j]);
          unsigned int u = __builtin_bit_cast(unsigned int, p);
          int prow = (m << 4) + (l4 << 2) + j;
          int pcol = (fn << 4) + lo;
          p_w[(prow << 6) + (pcol ^ ((prow & 7) << 3))] =
              (u16)((u + 0x8000u) >> 16);
        }
    // PV + ones-column rowsum
    __builtin_amdgcn_s_setprio(1);
#pragma unroll
    for (int ks = 0; ks < 2; ++ks) {
      const int kg = l4 + (ks << 2);
      bf16x8 pf[2], vf[4];
#pragma unroll
      for (int m = 0; m < 2; ++m) {
        int pr = (m << 4) + lo;
        pf[m] = *(const bf16x8*)(p_w + (pr << 6) + ((kg ^ (pr & 7)) << 3));
      }
#pragma unroll
      for (int fd = 0; fd < 4; ++fd) {
        int rd = (fd << 4) + lo;
        vf[fd] = *(const bf16x8*)(vb_ + (rd << 6) + ((kg ^ (rd & 7)) << 3));
      }
#pragma unroll
      for (int m = 0; m < 2; ++m) {
        osum[m] = __builtin_amdgcn_mfma_f32_16x16x32_bf16(
            pf[m], onesf, osum[m], 0, 0, 0);
#pragma unroll
        for (int fd = 0; fd < 4; ++fd)
          osoft[m][fd] = __builtin_amdgcn_mfma_f32_16x16x32_bf16(
              pf[m], vf[fd], osoft[m][fd], 0, 0, 0);
      }
    }
    __builtin_amdgcn_s_setprio(0);
    __syncthreads();
  }
  // epilogue
#pragma unroll
  for (int m = 0; m < 2; ++m) {
    f32x4 rl;
#pragma unroll
    for (int j = 0; j < 4; ++j) rl[j] = 1.0f / osum[m][j];
#pragma unroll
    for (int fd = 0; fd < 4; ++fd)
#pragma unroll
      for (int j = 0; j < 4; ++j) {
        int qrow = q0 + (m << 4) + (l4 << 2) + j;
        int e = (h << 6) + (fd << 4) + lo;
        size_t idx = (((size_t)(b * 1024 + qrow)) << 10) + e;
        float o = osoft[m][fd][j] * rl[j] + bf2f(xvg[idx]);
        xv[idx] = f2bf(o);
      }
  }
#undef STAGE
}

// ---------------------------------------------------------------------------
extern "C" void kernel_launch(void* const* d_in, const int* in_sizes, int n_in,
                              void* d_out, int out_size, void* d_ws, size_t ws_size,
                              hipStream_t stream) {
  (void)in_sizes; (void)n_in; (void)out_size; (void)ws_size;
  const float* x   = (const float*)d_in[0];
  const float* mask= (const float*)d_in[1];
  const float* gnn = (const float*)d_in[2];
  const float* Wq  = (const float*)d_in[3];
  const float* bq  = (const float*)d_in[4];
  const float* Wk  = (const float*)d_in[5];
  const float* bk  = (const float*)d_in[6];
  const float* Wv  = (const float*)d_in[7];
  const float* bv  = (const float*)d_in[8];
  const float* Wo  = (const float*)d_in[9];
  const float* bo  = (const float*)d_in[10];
  const float* g1  = (const float*)d_in[11];
  const float* b1  = (const float*)d_in[12];
  const float* g2  = (const float*)d_in[13];
  const float* b2  = (const float*)d_in[14];
  const float* W1  = (const float*)d_in[15];
  const float* bf1 = (const float*)d_in[16];
  const float* W2  = (const float*)d_in[17];
  const float* bf2 = (const float*)d_in[18];
  float* out = (float*)d_out;

  char* ws = (char*)d_ws;
  const size_t MB = 1024 * 1024;
  // layout (MB): 0-24 wt | 24-32 nx -> xv -> hbuf | 32-40 Q | 40-48 K
  // | 48-56 Vt | 56-64 biasI | 64-72 gnnbf | 72-80 vtmp -> xvg
  // post-attn: x1 fp32 64-80 | ff1 32-64
  u16*  wt    = (u16*)(ws);
  u16*  nx    = (u16*)(ws + 24 * MB);
  u16*  xvbuf = (u16*)(ws + 24 * MB);
  u16*  hbuf  = (u16*)(ws + 24 * MB);
  u16*  qk    = (u16*)(ws + 32 * MB);
  u16*  vt    = (u16*)(ws + 48 * MB);
  u16*  biasI = (u16*)(ws + 56 * MB);
  u16*  gnnbf = (u16*)(ws + 64 * MB);
  u16*  vtmp  = (u16*)(ws + 72 * MB);
  u16*  xvg   = (u16*)(ws + 72 * MB);
  float* x1   = (float*)(ws + 64 * MB);
  u16*  ff1   = (u16*)(ws + 32 * MB);

  cast_transpose_all<<<12288, 256, 0, stream>>>(Wq, Wk, Wv, Wo, W1, W2, wt);
  ln_kernel<<<4096, 256, 0, stream>>>(x, g1, b1, nx);
  cast_maskgnn<<<4096, 256, 0, stream>>>(mask, gnn, biasI, gnnbf);
  gemm_qkv<<<dim3(32, 8, 3), 256, 0, stream>>>(nx, wt, bq, bk, bv, qk, vtmp);
  vtrans_kernel<<<dim3(16, 16, 4), 256, 0, stream>>>(vtmp, vt);
  gemm_gnnv<<<dim3(16, 8, 4), 256, 0, stream>>>(gnnbf, vt, xvg);
  attn_kernel<<<512, 256, 0, stream>>>(
      qk, qk + (size_t)4 * MB, vt, biasI, xvg, xvbuf);
  gemm_wo<<<dim3(64, 8), 256, 0, stream>>>(xvbuf, wt + (size_t)3 * MB, bo, x, x1);
  ln_kernel<<<4096, 256, 0, stream>>>(x1, g2, b2, hbuf);
  gemm_w1<<<dim3(32, 32), 256, 0, stream>>>(hbuf, wt + (size_t)4 * MB, bf1, ff1);
  gemm_w2<<<dim3(64, 8), 256, 0, stream>>>(ff1, wt + (size_t)8 * MB, bf2, x1, out);
}

// Round 7
// 232.952 us; speedup vs baseline: 1.7389x; 1.0027x over previous
//
#include <hip/hip_runtime.h>
#include <hip/hip_bf16.h>

typedef unsigned short u16;
typedef short bf16x8 __attribute__((ext_vector_type(8)));
typedef float f32x4 __attribute__((ext_vector_type(4)));

#define B_ 4
#define S_ 1024
#define E_ 1024
#define H_ 16
#define FF_ 4096
#define D_ 64
#define M_ 4096  /* B*S */

__device__ __forceinline__ u16 f2bf(float f) {
  unsigned int u = __builtin_bit_cast(unsigned int, f);
  u += 0x7fffu + ((u >> 16) & 1u);   // RNE
  return (u16)(u >> 16);
}
__device__ __forceinline__ float bf2f(u16 v) {
  unsigned int u = ((unsigned int)v) << 16;
  return __builtin_bit_cast(float, u);
}

__device__ __forceinline__ void gld_lds16(const void* g, void* l) {
  __builtin_amdgcn_global_load_lds((__attribute__((address_space(1))) void*)g,
                                   (__attribute__((address_space(3))) void*)l,
                                   16, 0, 0);
}

// ---------------------------------------------------------------------------
// Weight cast+transpose: W (K x N fp32) -> Wt (N x K bf16), all 6 weights
// ---------------------------------------------------------------------------
__global__ void __launch_bounds__(256) cast_transpose_all(
    const float* __restrict__ wq, const float* __restrict__ wk,
    const float* __restrict__ wv, const float* __restrict__ wo,
    const float* __restrict__ w1, const float* __restrict__ w2,
    u16* __restrict__ wt) {
  int bid = blockIdx.x;
  const float* src; u16* dst; int K, N; int local;
  if (bid < 4096) {
    int wsel = bid >> 10; local = bid & 1023; K = 1024; N = 1024;
    src = wsel == 0 ? wq : wsel == 1 ? wk : wsel == 2 ? wv : wo;
    dst = wt + (size_t)wsel * 1024 * 1024;
  } else if (bid < 8192) {
    local = bid - 4096; K = 1024; N = 4096; src = w1;
    dst = wt + (size_t)4 * 1024 * 1024;
  } else {
    local = bid - 8192; K = 4096; N = 1024; src = w2;
    dst = wt + (size_t)8 * 1024 * 1024;
  }
  int tiles_n = N >> 5;
  int n0 = (local % tiles_n) << 5, k0 = (local / tiles_n) << 5;
  __shared__ float tl[32][33];
  int tx = threadIdx.x & 31, ty = threadIdx.x >> 5;
#pragma unroll
  for (int i = 0; i < 4; ++i)
    tl[ty + i * 8][tx] = src[(size_t)(k0 + ty + i * 8) * N + n0 + tx];
  __syncthreads();
#pragma unroll
  for (int i = 0; i < 4; ++i)
    dst[(size_t)(n0 + ty + i * 8) * K + k0 + tx] = f2bf(tl[tx][ty + i * 8]);
}

// ---------------------------------------------------------------------------
// mask -> additive C-init bias (exp2 domain, fixed shift C=8); gnn -> bf16
// ---------------------------------------------------------------------------
__global__ void __launch_bounds__(256) cast_maskgnn(
    const float* __restrict__ mask, const float* __restrict__ gnn,
    u16* __restrict__ biasI, u16* __restrict__ gnnbf) {
  int row = blockIdx.x;             // b*1024 + q
  int b = row >> 10, q = row & 1023;
  int t = threadIdx.x;
  __shared__ float mrow[1024];
  const float* mp = mask + ((size_t)row << 10);
  const float* gp = gnn + ((size_t)row << 10);
  float4 mv = *(const float4*)(mp + t * 4);
  *(float4*)(mrow + t * 4) = mv;
  float4 gv = *(const float4*)(gp + t * 4);
  ushort4 g4;
  g4.x = f2bf(gv.x); g4.y = f2bf(gv.y); g4.z = f2bf(gv.z); g4.w = f2bf(gv.w);
  *(ushort4*)(gnnbf + ((size_t)row << 10) + t * 4) = g4;
  __syncthreads();
  int kt = t >> 4, c = t & 15;
  const u16 NEG = f2bf(-30008.f);
  const u16 SHIFT = f2bf(-8.0f);
  ushort4 o;
  o.x = (mrow[kt * 64 + c] == 0.f) ? NEG : SHIFT;
  o.y = (mrow[kt * 64 + 16 + c] == 0.f) ? NEG : SHIFT;
  o.z = (mrow[kt * 64 + 32 + c] == 0.f) ? NEG : SHIFT;
  o.w = (mrow[kt * 64 + 48 + c] == 0.f) ? NEG : SHIFT;
  *(ushort4*)(biasI + (((size_t)(b * 16 + kt) << 10) + q) * 64 + c * 4) = o;
}

// ---------------------------------------------------------------------------
// V (b,h,s,d) -> Vt (b, h*64+d, s)
// ---------------------------------------------------------------------------
__global__ void __launch_bounds__(256) vtrans_kernel(
    const u16* __restrict__ v, u16* __restrict__ vt) {
  int st = blockIdx.x, h = blockIdx.y, b = blockIdx.z;
  __shared__ u16 tl[64][72];
  const u16* src = v + ((((size_t)(b * 16 + h)) << 10) + (st << 6)) * 64;
  int r = threadIdx.x >> 2, g = (threadIdx.x & 3) << 4;
  *(uint4*)&tl[r][g] = *(const uint4*)(src + r * 64 + g);
  *(uint4*)&tl[r][g + 8] = *(const uint4*)(src + r * 64 + g + 8);
  __syncthreads();
  u16 tmp[16];
#pragma unroll
  for (int i = 0; i < 16; ++i) tmp[i] = tl[g + i][r];
  u16* dst = vt + ((size_t)b << 20) + (((size_t)(h * 64 + r)) << 10) + (st << 6) + g;
  *(uint4*)(dst) = *(uint4*)(tmp);
  *(uint4*)(dst + 8) = *(uint4*)(tmp + 8);
}

// ---------------------------------------------------------------------------
// LayerNorm fp32-in -> bf16. One block per row.
// ---------------------------------------------------------------------------
__global__ void __launch_bounds__(256) ln_kernel(
    const float* __restrict__ x, const float* __restrict__ g,
    const float* __restrict__ bt, u16* __restrict__ out) {
  int row = blockIdx.x, t = threadIdx.x;
  const float* xr = x + (size_t)row * 1024;
  float4 v = *(const float4*)(xr + t * 4);
  float s = v.x + v.y + v.z + v.w;
  float q = v.x * v.x + v.y * v.y + v.z * v.z + v.w * v.w;
#pragma unroll
  for (int off = 1; off < 64; off <<= 1) {
    s += __shfl_xor(s, off);
    q += __shfl_xor(q, off);
  }
  __shared__ float sb[4], qb[4];
  int w = t >> 6, l = t & 63;
  if (l == 0) { sb[w] = s; qb[w] = q; }
  __syncthreads();
  s = sb[0] + sb[1] + sb[2] + sb[3];
  q = qb[0] + qb[1] + qb[2] + qb[3];
  float mean = s * (1.f / 1024.f);
  float var = q * (1.f / 1024.f) - mean * mean;
  float rs = rsqrtf(var + 1e-5f);
  float4 gv = *(const float4*)(g + t * 4);
  float4 bv = *(const float4*)(bt + t * 4);
  ushort4 o;
  o.x = f2bf((v.x - mean) * rs * gv.x + bv.x);
  o.y = f2bf((v.y - mean) * rs * gv.y + bv.y);
  o.z = f2bf((v.z - mean) * rs * gv.z + bv.z);
  o.w = f2bf((v.w - mean) * rs * gv.w + bv.w);
  *(ushort4*)(out + (size_t)row * 1024 + t * 4) = o;
}

// --- LayerNorm bf16-in -> bf16 ----------------------------------------------
__global__ void __launch_bounds__(256) ln_kernel_b(
    const u16* __restrict__ x, const float* __restrict__ g,
    const float* __restrict__ bt, u16* __restrict__ out) {
  int row = blockIdx.x, t = threadIdx.x;
  const u16* xr = x + ((size_t)row << 10);
  ushort4 xv4 = *(const ushort4*)(xr + t * 4);
  float v0 = bf2f(xv4.x), v1 = bf2f(xv4.y), v2 = bf2f(xv4.z), v3 = bf2f(xv4.w);
  float s = v0 + v1 + v2 + v3;
  float q = v0 * v0 + v1 * v1 + v2 * v2 + v3 * v3;
#pragma unroll
  for (int off = 1; off < 64; off <<= 1) {
    s += __shfl_xor(s, off);
    q += __shfl_xor(q, off);
  }
  __shared__ float sb[4], qb[4];
  int w = t >> 6, l = t & 63;
  if (l == 0) { sb[w] = s; qb[w] = q; }
  __syncthreads();
  s = sb[0] + sb[1] + sb[2] + sb[3];
  q = qb[0] + qb[1] + qb[2] + qb[3];
  float mean = s * (1.f / 1024.f);
  float var = q * (1.f / 1024.f) - mean * mean;
  float rs = rsqrtf(var + 1e-5f);
  float4 gv = *(const float4*)(g + t * 4);
  float4 bv = *(const float4*)(bt + t * 4);
  ushort4 o;
  o.x = f2bf((v0 - mean) * rs * gv.x + bv.x);
  o.y = f2bf((v1 - mean) * rs * gv.y + bv.y);
  o.z = f2bf((v2 - mean) * rs * gv.z + bv.z);
  o.w = f2bf((v3 - mean) * rs * gv.w + bv.w);
  *(ushort4*)(out + ((size_t)row << 10) + t * 4) = o;
}

// ---------------------------------------------------------------------------
// Double-buffered GEMM core 64x128, BK=64. 48 KiB LDS -> 3 blocks/CU.
// Waves 1x4: wave w covers all 64 rows x cols [w*32, w*32+32).
// ---------------------------------------------------------------------------
__device__ __forceinline__ void gemm_core_db64(
    const u16* __restrict__ A, int lda, const u16* __restrict__ Bt, int ldb,
    int nkt, int bm, int bn, u16* lds, f32x4 acc[4][2]) {
  const int tid = threadIdx.x;
  const int w = tid >> 6, l = tid & 63;
  const int wn = w << 5;
  const int lrow = l >> 3;
  const int cg = (l & 7) ^ lrow;
  const u16* Ab = A + (size_t)(bm << 6) * lda;
  const u16* Bb = Bt + (size_t)(bn << 7) * ldb;
#define GSTAGE64(T, BUF)                                                     \
  {                                                                          \
    int kk = (T) << 6;                                                       \
    u16* la = lds + (BUF) * 12288;                                           \
    u16* lb = la + 4096;                                                     \
    _Pragma("unroll") for (int i = 0; i < 2; ++i) {                          \
      int c = (w << 1) + i;                                                  \
      int row = (c << 3) + lrow;                                             \
      gld_lds16(Ab + (size_t)row * lda + kk + (cg << 3), la + (c << 9));     \
    }                                                                        \
    _Pragma("unroll") for (int i = 0; i < 4; ++i) {                          \
      int c = (w << 2) + i;                                                  \
      int row = (c << 3) + lrow;                                             \
      gld_lds16(Bb + (size_t)row * ldb + kk + (cg << 3), lb + (c << 9));     \
    }                                                                        \
  }
  GSTAGE64(0, 0);
  __syncthreads();
  for (int t = 0; t < nkt; ++t) {
    if (t + 1 < nkt) GSTAGE64(t + 1, (t & 1) ^ 1);
    const u16* la = lds + (t & 1) * 12288;
    const u16* lb = la + 4096;
    bf16x8 af[2][4], bfr[2][2];
    const int rr = l & 15;
    const int kgb = l >> 4;
#pragma unroll
    for (int ks = 0; ks < 2; ++ks) {
      const int kg = kgb + (ks << 2);
#pragma unroll
      for (int f = 0; f < 4; ++f) {
        int ra = (f << 4) + rr;
        af[ks][f] = *(const bf16x8*)(la + (ra << 6) + ((kg ^ (ra & 7)) << 3));
      }
#pragma unroll
      for (int f = 0; f < 2; ++f) {
        int rb = wn + (f << 4) + rr;
        bfr[ks][f] = *(const bf16x8*)(lb + (rb << 6) + ((kg ^ (rb & 7)) << 3));
      }
    }
#pragma unroll
    for (int fm = 0; fm < 4; ++fm)
#pragma unroll
      for (int fn = 0; fn < 2; ++fn)
#pragma unroll
        for (int ks = 0; ks < 2; ++ks)
          acc[fm][fn] = __builtin_amdgcn_mfma_f32_16x16x32_bf16(
              af[ks][fm], bfr[ks][fn], acc[fm][fn], 0, 0, 0);
    __syncthreads();
  }
#undef GSTAGE64
}

#define ACC_INIT64()                      \
  f32x4 acc[4][2];                        \
  { f32x4 zf = {0.f, 0.f, 0.f, 0.f};      \
_Pragma("unroll")                         \
    for (int a = 0; a < 4; ++a)           \
_Pragma("unroll")                         \
      for (int bb = 0; bb < 2; ++bb) acc[a][bb] = zf; }

#define EPI_SETUP64()                                   \
  const int w = threadIdx.x >> 6, l = threadIdx.x & 63; \
  const int wn = w << 5;

#define GEMM_LDS64() __shared__ __attribute__((aligned(16))) u16 lds[2 * 12288]

// --- QKV: 64-row tiles; all z write (b,h,s,d); z=2 -> vtmp; Q pre-scaled -----
__global__ void __launch_bounds__(256, 2) gemm_qkv(
    const u16* __restrict__ nx, const u16* __restrict__ wt,
    const float* __restrict__ bq, const float* __restrict__ bk,
    const float* __restrict__ bv, u16* __restrict__ qk, u16* __restrict__ vtmp) {
  GEMM_LDS64();
  ACC_INIT64();
  int z = blockIdx.z;
  const u16* Bt = wt + (size_t)z * 1024 * 1024;
  const float* bias = z == 0 ? bq : z == 1 ? bk : bv;
  u16* out = z == 2 ? vtmp : qk + (size_t)z * M_ * 1024;
  const float scl = (z == 0) ? 0.18033688f : 1.0f;  // 0.125*log2(e) for Q
  gemm_core_db64(nx, 1024, Bt, 1024, 16, blockIdx.x, blockIdx.y, lds, acc);
  EPI_SETUP64();
#pragma unroll
  for (int fm = 0; fm < 4; ++fm)
#pragma unroll
    for (int fn = 0; fn < 2; ++fn)
#pragma unroll
      for (int j = 0; j < 4; ++j) {
        int row = (blockIdx.x << 6) + (fm << 4) + ((l >> 4) << 2) + j;
        int col = (blockIdx.y << 7) + wn + (fn << 4) + (l & 15);
        float v = (acc[fm][fn][j] + bias[col]) * scl;
        int b = row >> 10, s = row & 1023;
        int h = col >> 6, d = col & 63;
        out[(((size_t)(b * 16 + h) << 10) + s) * 64 + d] = f2bf(v);
      }
}

// --- gnnV: xvg[b,q,e] = gnnbf[b] @ Vt[b]^T (bf16 out) ------------------------
__global__ void __launch_bounds__(256, 2) gemm_gnnv(
    const u16* __restrict__ gnnbf, const u16* __restrict__ vt,
    u16* __restrict__ xvg) {
  GEMM_LDS64();
  ACC_INIT64();
  int b = blockIdx.z;
  const u16* A = gnnbf + ((size_t)b << 20);
  const u16* Bt = vt + ((size_t)b << 20);
  u16* out = xvg + ((size_t)b << 20);
  gemm_core_db64(A, 1024, Bt, 1024, 16, blockIdx.x, blockIdx.y, lds, acc);
  EPI_SETUP64();
#pragma unroll
  for (int fm = 0; fm < 4; ++fm)
#pragma unroll
    for (int fn = 0; fn < 2; ++fn)
#pragma unroll
      for (int j = 0; j < 4; ++j) {
        int row = (blockIdx.x << 6) + (fm << 4) + ((l >> 4) << 2) + j;
        int col = (blockIdx.y << 7) + wn + (fn << 4) + (l & 15);
        out[((size_t)row << 10) + col] = f2bf(acc[fm][fn][j]);
      }
}

// --- Wo: x1b = bf16(x + xv@Wo + bo) ------------------------------------------
__global__ void __launch_bounds__(256, 2) gemm_wo(
    const u16* __restrict__ xv, const u16* __restrict__ wt,
    const float* __restrict__ bo, const float* __restrict__ xres,
    u16* __restrict__ x1b) {
  GEMM_LDS64();
  ACC_INIT64();
  gemm_core_db64(xv, 1024, wt, 1024, 16, blockIdx.x, blockIdx.y, lds, acc);
  EPI_SETUP64();
#pragma unroll
  for (int fm = 0; fm < 4; ++fm)
#pragma unroll
    for (int fn = 0; fn < 2; ++fn)
#pragma unroll
      for (int j = 0; j < 4; ++j) {
        int row = (blockIdx.x << 6) + (fm << 4) + ((l >> 4) << 2) + j;
        int col = (blockIdx.y << 7) + wn + (fn << 4) + (l & 15);
        size_t idx = ((size_t)row << 10) + col;
        x1b[idx] = f2bf(acc[fm][fn][j] + bo[col] + xres[idx]);
      }
}

// --- W1: ff1 = gelu(h@W1 + bf1) bf16 (M x FF), 64-row tiles ------------------
__global__ void __launch_bounds__(256, 2) gemm_w1(
    const u16* __restrict__ hb, const u16* __restrict__ wt,
    const float* __restrict__ bf1, u16* __restrict__ ff1) {
  GEMM_LDS64();
  ACC_INIT64();
  gemm_core_db64(hb, 1024, wt, 1024, 16, blockIdx.x, blockIdx.y, lds, acc);
  EPI_SETUP64();
#pragma unroll
  for (int fm = 0; fm < 4; ++fm)
#pragma unroll
    for (int fn = 0; fn < 2; ++fn)
#pragma unroll
      for (int j = 0; j < 4; ++j) {
        int row = (blockIdx.x << 6) + (fm << 4) + ((l >> 4) << 2) + j;
        int col = (blockIdx.y << 7) + wn + (fn << 4) + (l & 15);
        float v = acc[fm][fn][j] + bf1[col];
        float ge = 0.5f * v * (1.f + erff(v * 0.70710678118654752f));
        ff1[((size_t)row << 12) + col] = f2bf(ge);
      }
}

// --- W2: out = x1b + ff1@W2 + bf2 (fp32, K=4096), 64-row tiles ---------------
__global__ void __launch_bounds__(256, 2) gemm_w2(
    const u16* __restrict__ ff1, const u16* __restrict__ wt,
    const float* __restrict__ bf2, const u16* __restrict__ x1b,
    float* __restrict__ out) {
  GEMM_LDS64();
  ACC_INIT64();
  gemm_core_db64(ff1, 4096, wt, 4096, 64, blockIdx.x, blockIdx.y, lds, acc);
  EPI_SETUP64();
#pragma unroll
  for (int fm = 0; fm < 4; ++fm)
#pragma unroll
    for (int fn = 0; fn < 2; ++fn)
#pragma unroll
      for (int j = 0; j < 4; ++j) {
        int row = (blockIdx.x << 6) + (fm << 4) + ((l >> 4) << 2) + j;
        int col = (blockIdx.y << 7) + wn + (fn << 4) + (l & 15);
        size_t idx = ((size_t)row << 10) + col;
        out[idx] = acc[fm][fn][j] + bf2[col] + bf2f(x1b[idx]);
      }
}

// ---------------------------------------------------------------------------
// Flash attention, fixed-shift softmax (C=8, exp2 domain).
// Grid: 512 blocks (XCD-chunked); 4 waves x 32 q-rows; KV tile 64.
// ---------------------------------------------------------------------------
__global__ void __launch_bounds__(256, 2) attn_kernel(
    const u16* __restrict__ Q, const u16* __restrict__ K,
    const u16* __restrict__ Vt, const u16* __restrict__ biasI,
    const u16* __restrict__ xvg, u16* __restrict__ xv) {
  const int lin = ((blockIdx.x & 7) << 6) + (blockIdx.x >> 3);  // XCD chunk
  const int qt = lin & 7, h = (lin >> 3) & 15, b = lin >> 7;
  const int tid = threadIdx.x, w = tid >> 6, l = tid & 63;
  __shared__ __attribute__((aligned(16))) u16 kbuf[2][64 * 64];
  __shared__ __attribute__((aligned(16))) u16 vbuf[2][64 * 64];
  __shared__ __attribute__((aligned(16))) u16 pbuf[4][32 * 64];
  const size_t bh = ((size_t)(b * 16 + h)) << 16;
  const u16* Qb = Q + bh;
  const u16* Kb = K + bh;
  const u16* Vtb = Vt + ((size_t)b << 20) + ((size_t)(h * 64) << 10);
  const u16* biasb = biasI + ((size_t)b << 20);
  const int q0 = (qt << 7) + (w << 5);
  const int lrow = l >> 3, cg = (l & 7) ^ lrow;
  const int l4 = l >> 4, lo = l & 15;
  u16* p_w = pbuf[w];

  bf16x8 qf[2][2];
#pragma unroll
  for (int m = 0; m < 2; ++m)
#pragma unroll
    for (int ks = 0; ks < 2; ++ks)
      qf[m][ks] = *(const bf16x8*)(Qb + ((size_t)(q0 + m * 16 + lo) << 6) +
                                   l4 * 8 + ks * 32);
  bf16x8 onesf;
#pragma unroll
  for (int j = 0; j < 8; ++j) onesf[j] = (short)0x3F80;

  f32x4 osoft[2][4], osum[2];
  f32x4 zf = {0.f, 0.f, 0.f, 0.f};
#pragma unroll
  for (int m = 0; m < 2; ++m) {
    osum[m] = zf;
#pragma unroll
    for (int fd = 0; fd < 4; ++fd) osoft[m][fd] = zf;
  }

#define STAGE(T, BUF)                                                          \
  {                                                                            \
    int kv0s = (T) << 6;                                                       \
    u16* kd = &kbuf[BUF][0];                                                   \
    u16* vd = &vbuf[BUF][0];                                                   \
    _Pragma("unroll") for (int i = 0; i < 2; ++i) {                            \
      int c = (w << 1) + i;                                                    \
      gld_lds16(Kb + ((size_t)(kv0s + (c << 3) + lrow) << 6) + (cg << 3),      \
                kd + (c << 9));                                                \
      gld_lds16(Vtb + ((size_t)((c << 3) + lrow) << 10) + kv0s + (cg << 3),    \
                vd + (c << 9));                                                \
    }                                                                          \
  }

  STAGE(0, 0);
  __syncthreads();

  for (int t = 0; t < 16; ++t) {
    const int cur = t & 1;
    if (t < 15) STAGE(t + 1, cur ^ 1);
    const u16* kb_ = &kbuf[cur][0];
    const u16* vb_ = &vbuf[cur][0];
    // C-init from bias (holds -8 / -30008 in exp2 domain)
    f32x4 sacc[2][4];
#pragma unroll
    for (int m = 0; m < 2; ++m)
#pragma unroll
      for (int j = 0; j < 4; ++j) {
        ushort4 bb = *(const ushort4*)(
            biasb + (((size_t)(t * 1024 + q0 + m * 16 + l4 * 4 + j)) << 6) +
            lo * 4);
        sacc[m][0][j] = bf2f(bb.x);
        sacc[m][1][j] = bf2f(bb.y);
        sacc[m][2][j] = bf2f(bb.z);
        sacc[m][3][j] = bf2f(bb.w);
      }
    // QK^T
    __builtin_amdgcn_s_setprio(1);
#pragma unroll
    for (int ks = 0; ks < 2; ++ks) {
      const int kg = l4 + (ks << 2);
      bf16x8 kf[4];
#pragma unroll
      for (int fn = 0; fn < 4; ++fn) {
        int rk = (fn << 4) + lo;
        kf[fn] = *(const bf16x8*)(kb_ + (rk << 6) + ((kg ^ (rk & 7)) << 3));
      }
#pragma unroll
      for (int m = 0; m < 2; ++m)
#pragma unroll
        for (int fn = 0; fn < 4; ++fn)
          sacc[m][fn] = __builtin_amdgcn_mfma_f32_16x16x32_bf16(
              qf[m][ks], kf[fn], sacc[m][fn], 0, 0, 0);
    }
    __builtin_amdgcn_s_setprio(0);
    // P = exp2(s), pack to bf16, store to per-wave LDS
#pragma unroll
    for (int m = 0; m < 2; ++m)
#pragma unroll
      for (int fn = 0; fn < 4; ++fn)
#pragma unroll
        for (int j = 0; j < 4; ++j) {
          float p = exp2f(sacc[m][fn][j]);
          unsigned int u = __builtin_bit_cast(unsigned int, p);
          int prow = (m << 4) + (l4 << 2) + j;
          int pcol = (fn << 4) + lo;
          p_w[(prow << 6) + (pcol ^ ((prow & 7) << 3))] =
              (u16)((u + 0x8000u) >> 16);
        }
    // PV + ones-column rowsum
    __builtin_amdgcn_s_setprio(1);
#pragma unroll
    for (int ks = 0; ks < 2; ++ks) {
      const int kg = l4 + (ks << 2);
      bf16x8 pf[2], vf[4];
#pragma unroll
      for (int m = 0; m < 2; ++m) {
        int pr = (m << 4) + lo;
        pf[m] = *(const bf16x8*)(p_w + (pr << 6) + ((kg ^ (pr & 7)) << 3));
      }
#pragma unroll
      for (int fd = 0; fd < 4; ++fd) {
        int rd = (fd << 4) + lo;
        vf[fd] = *(const bf16x8*)(vb_ + (rd << 6) + ((kg ^ (rd & 7)) << 3));
      }
#pragma unroll
      for (int m = 0; m < 2; ++m) {
        osum[m] = __builtin_amdgcn_mfma_f32_16x16x32_bf16(
            pf[m], onesf, osum[m], 0, 0, 0);
#pragma unroll
        for (int fd = 0; fd < 4; ++fd)
          osoft[m][fd] = __builtin_amdgcn_mfma_f32_16x16x32_bf16(
              pf[m], vf[fd], osoft[m][fd], 0, 0, 0);
      }
    }
    __builtin_amdgcn_s_setprio(0);
    __syncthreads();
  }
  // epilogue
#pragma unroll
  for (int m = 0; m < 2; ++m) {
    f32x4 rl;
#pragma unroll
    for (int j = 0; j < 4; ++j) rl[j] = 1.0f / osum[m][j];
#pragma unroll
    for (int fd = 0; fd < 4; ++fd)
#pragma unroll
      for (int j = 0; j < 4; ++j) {
        int qrow = q0 + (m << 4) + (l4 << 2) + j;
        int e = (h << 6) + (fd << 4) + lo;
        size_t idx = (((size_t)(b * 1024 + qrow)) << 10) + e;
        float o = osoft[m][fd][j] * rl[j] + bf2f(xvg[idx]);
        xv[idx] = f2bf(o);
      }
  }
#undef STAGE
}

// ---------------------------------------------------------------------------
extern "C" void kernel_launch(void* const* d_in, const int* in_sizes, int n_in,
                              void* d_out, int out_size, void* d_ws, size_t ws_size,
                              hipStream_t stream) {
  (void)in_sizes; (void)n_in; (void)out_size; (void)ws_size;
  const float* x   = (const float*)d_in[0];
  const float* mask= (const float*)d_in[1];
  const float* gnn = (const float*)d_in[2];
  const float* Wq  = (const float*)d_in[3];
  const float* bq  = (const float*)d_in[4];
  const float* Wk  = (const float*)d_in[5];
  const float* bk  = (const float*)d_in[6];
  const float* Wv  = (const float*)d_in[7];
  const float* bv  = (const float*)d_in[8];
  const float* Wo  = (const float*)d_in[9];
  const float* bo  = (const float*)d_in[10];
  const float* g1  = (const float*)d_in[11];
  const float* b1  = (const float*)d_in[12];
  const float* g2  = (const float*)d_in[13];
  const float* b2  = (const float*)d_in[14];
  const float* W1  = (const float*)d_in[15];
  const float* bf1 = (const float*)d_in[16];
  const float* W2  = (const float*)d_in[17];
  const float* bf2 = (const float*)d_in[18];
  float* out = (float*)d_out;

  char* ws = (char*)d_ws;
  const size_t MB = 1024 * 1024;
  // layout (MB): 0-24 wt | 24-32 nx -> xvbuf -> hbuf | 32-40 Q | 40-48 K
  // | 48-56 Vt | 56-64 biasI | 64-72 gnnbf -> x1b | 72-80 vtmp -> xvg
  // post-attn: ff1 32-64
  u16*  wt    = (u16*)(ws);
  u16*  nx    = (u16*)(ws + 24 * MB);
  u16*  xvbuf = (u16*)(ws + 24 * MB);
  u16*  hbuf  = (u16*)(ws + 24 * MB);
  u16*  qk    = (u16*)(ws + 32 * MB);
  u16*  vt    = (u16*)(ws + 48 * MB);
  u16*  biasI = (u16*)(ws + 56 * MB);
  u16*  gnnbf = (u16*)(ws + 64 * MB);
  u16*  x1b   = (u16*)(ws + 64 * MB);
  u16*  vtmp  = (u16*)(ws + 72 * MB);
  u16*  xvg   = (u16*)(ws + 72 * MB);
  u16*  ff1   = (u16*)(ws + 32 * MB);

  cast_transpose_all<<<12288, 256, 0, stream>>>(Wq, Wk, Wv, Wo, W1, W2, wt);
  ln_kernel<<<4096, 256, 0, stream>>>(x, g1, b1, nx);
  cast_maskgnn<<<4096, 256, 0, stream>>>(mask, gnn, biasI, gnnbf);
  gemm_qkv<<<dim3(64, 8, 3), 256, 0, stream>>>(nx, wt, bq, bk, bv, qk, vtmp);
  vtrans_kernel<<<dim3(16, 16, 4), 256, 0, stream>>>(vtmp, vt);
  gemm_gnnv<<<dim3(16, 8, 4), 256, 0, stream>>>(gnnbf, vt, xvg);
  attn_kernel<<<512, 256, 0, stream>>>(
      qk, qk + (size_t)4 * MB, vt, biasI, xvg, xvbuf);
  gemm_wo<<<dim3(64, 8), 256, 0, stream>>>(xvbuf, wt + (size_t)3 * MB, bo, x, x1b);
  ln_kernel_b<<<4096, 256, 0, stream>>>(x1b, g2, b2, hbuf);
  gemm_w1<<<dim3(64, 32), 256, 0, stream>>>(hbuf, wt + (size_t)4 * MB, bf1, ff1);
  gemm_w2<<<dim3(64, 8), 256, 0, stream>>>(ff1, wt + (size_t)8 * MB, bf2, x1b, out);
}

// Round 8
// 230.744 us; speedup vs baseline: 1.7556x; 1.0096x over previous
//
#include <hip/hip_runtime.h>
#include <hip/hip_bf16.h>

typedef unsigned short u16;
typedef short bf16x8 __attribute__((ext_vector_type(8)));
typedef float f32x4 __attribute__((ext_vector_type(4)));

#define B_ 4
#define S_ 1024
#define E_ 1024
#define H_ 16
#define FF_ 4096
#define D_ 64
#define M_ 4096  /* B*S */

__device__ __forceinline__ u16 f2bf(float f) {
  unsigned int u = __builtin_bit_cast(unsigned int, f);
  u += 0x7fffu + ((u >> 16) & 1u);   // RNE
  return (u16)(u >> 16);
}
__device__ __forceinline__ float bf2f(u16 v) {
  unsigned int u = ((unsigned int)v) << 16;
  return __builtin_bit_cast(float, u);
}

__device__ __forceinline__ void gld_lds16(const void* g, void* l) {
  __builtin_amdgcn_global_load_lds((__attribute__((address_space(1))) void*)g,
                                   (__attribute__((address_space(3))) void*)l,
                                   16, 0, 0);
}

// ---------------------------------------------------------------------------
// Fused prologue: [0,12288) weight cast+transpose; [12288,16384) LN1;
// [16384,20480) mask->bias + gnn->bf16. All independent, one launch.
// ---------------------------------------------------------------------------
__global__ void __launch_bounds__(256) pre_kernel(
    const float* __restrict__ wq, const float* __restrict__ wk,
    const float* __restrict__ wv, const float* __restrict__ wo,
    const float* __restrict__ w1, const float* __restrict__ w2,
    u16* __restrict__ wt,
    const float* __restrict__ x, const float* __restrict__ g1,
    const float* __restrict__ b1, u16* __restrict__ nx,
    const float* __restrict__ mask, const float* __restrict__ gnn,
    u16* __restrict__ biasI, u16* __restrict__ gnnbf) {
  __shared__ __attribute__((aligned(16))) float smem_f[1088];
  int bid = blockIdx.x;
  int t = threadIdx.x;
  if (bid < 12288) {
    // ---- weight cast+transpose ----
    const float* src; u16* dst; int K, N; int local;
    if (bid < 4096) {
      int wsel = bid >> 10; local = bid & 1023; K = 1024; N = 1024;
      src = wsel == 0 ? wq : wsel == 1 ? wk : wsel == 2 ? wv : wo;
      dst = wt + (size_t)wsel * 1024 * 1024;
    } else if (bid < 8192) {
      local = bid - 4096; K = 1024; N = 4096; src = w1;
      dst = wt + (size_t)4 * 1024 * 1024;
    } else {
      local = bid - 8192; K = 4096; N = 1024; src = w2;
      dst = wt + (size_t)8 * 1024 * 1024;
    }
    int tiles_n = N >> 5;
    int n0 = (local % tiles_n) << 5, k0 = (local / tiles_n) << 5;
    float (*tl)[33] = reinterpret_cast<float(*)[33]>(smem_f);
    int tx = t & 31, ty = t >> 5;
#pragma unroll
    for (int i = 0; i < 4; ++i)
      tl[ty + i * 8][tx] = src[(size_t)(k0 + ty + i * 8) * N + n0 + tx];
    __syncthreads();
#pragma unroll
    for (int i = 0; i < 4; ++i)
      dst[(size_t)(n0 + ty + i * 8) * K + k0 + tx] = f2bf(tl[tx][ty + i * 8]);
  } else if (bid < 16384) {
    // ---- LayerNorm 1 (fp32 -> bf16) ----
    int row = bid - 12288;
    const float* xr = x + (size_t)row * 1024;
    float4 v = *(const float4*)(xr + t * 4);
    float s = v.x + v.y + v.z + v.w;
    float q = v.x * v.x + v.y * v.y + v.z * v.z + v.w * v.w;
#pragma unroll
    for (int off = 1; off < 64; off <<= 1) {
      s += __shfl_xor(s, off);
      q += __shfl_xor(q, off);
    }
    float* sb = smem_f;
    float* qb = smem_f + 4;
    int w = t >> 6, l = t & 63;
    if (l == 0) { sb[w] = s; qb[w] = q; }
    __syncthreads();
    s = sb[0] + sb[1] + sb[2] + sb[3];
    q = qb[0] + qb[1] + qb[2] + qb[3];
    float mean = s * (1.f / 1024.f);
    float var = q * (1.f / 1024.f) - mean * mean;
    float rs = rsqrtf(var + 1e-5f);
    float4 gv = *(const float4*)(g1 + t * 4);
    float4 bv = *(const float4*)(b1 + t * 4);
    ushort4 o;
    o.x = f2bf((v.x - mean) * rs * gv.x + bv.x);
    o.y = f2bf((v.y - mean) * rs * gv.y + bv.y);
    o.z = f2bf((v.z - mean) * rs * gv.z + bv.z);
    o.w = f2bf((v.w - mean) * rs * gv.w + bv.w);
    *(ushort4*)(nx + (size_t)row * 1024 + t * 4) = o;
  } else {
    // ---- mask -> C-init bias (exp2 domain, C=8); gnn -> bf16 ----
    int row = bid - 16384;
    int b = row >> 10, q = row & 1023;
    float* mrow = smem_f;
    const float* mp = mask + ((size_t)row << 10);
    const float* gp = gnn + ((size_t)row << 10);
    float4 mv = *(const float4*)(mp + t * 4);
    *(float4*)(mrow + t * 4) = mv;
    float4 gv = *(const float4*)(gp + t * 4);
    ushort4 g4;
    g4.x = f2bf(gv.x); g4.y = f2bf(gv.y); g4.z = f2bf(gv.z); g4.w = f2bf(gv.w);
    *(ushort4*)(gnnbf + ((size_t)row << 10) + t * 4) = g4;
    __syncthreads();
    int kt = t >> 4, c = t & 15;
    const u16 NEG = f2bf(-30008.f);
    const u16 SHIFT = f2bf(-8.0f);
    ushort4 o;
    o.x = (mrow[kt * 64 + c] == 0.f) ? NEG : SHIFT;
    o.y = (mrow[kt * 64 + 16 + c] == 0.f) ? NEG : SHIFT;
    o.z = (mrow[kt * 64 + 32 + c] == 0.f) ? NEG : SHIFT;
    o.w = (mrow[kt * 64 + 48 + c] == 0.f) ? NEG : SHIFT;
    *(ushort4*)(biasI + (((size_t)(b * 16 + kt) << 10) + q) * 64 + c * 4) = o;
  }
}

// ---------------------------------------------------------------------------
// V (b,h,s,d) -> Vt (b, h*64+d, s)
// ---------------------------------------------------------------------------
__global__ void __launch_bounds__(256) vtrans_kernel(
    const u16* __restrict__ v, u16* __restrict__ vt) {
  int st = blockIdx.x, h = blockIdx.y, b = blockIdx.z;
  __shared__ u16 tl[64][72];
  const u16* src = v + ((((size_t)(b * 16 + h)) << 10) + (st << 6)) * 64;
  int r = threadIdx.x >> 2, g = (threadIdx.x & 3) << 4;
  *(uint4*)&tl[r][g] = *(const uint4*)(src + r * 64 + g);
  *(uint4*)&tl[r][g + 8] = *(const uint4*)(src + r * 64 + g + 8);
  __syncthreads();
  u16 tmp[16];
#pragma unroll
  for (int i = 0; i < 16; ++i) tmp[i] = tl[g + i][r];
  u16* dst = vt + ((size_t)b << 20) + (((size_t)(h * 64 + r)) << 10) + (st << 6) + g;
  *(uint4*)(dst) = *(uint4*)(tmp);
  *(uint4*)(dst + 8) = *(uint4*)(tmp + 8);
}

// --- LayerNorm bf16-in -> bf16 ----------------------------------------------
__global__ void __launch_bounds__(256) ln_kernel_b(
    const u16* __restrict__ x, const float* __restrict__ g,
    const float* __restrict__ bt, u16* __restrict__ out) {
  int row = blockIdx.x, t = threadIdx.x;
  const u16* xr = x + ((size_t)row << 10);
  ushort4 xv4 = *(const ushort4*)(xr + t * 4);
  float v0 = bf2f(xv4.x), v1 = bf2f(xv4.y), v2 = bf2f(xv4.z), v3 = bf2f(xv4.w);
  float s = v0 + v1 + v2 + v3;
  float q = v0 * v0 + v1 * v1 + v2 * v2 + v3 * v3;
#pragma unroll
  for (int off = 1; off < 64; off <<= 1) {
    s += __shfl_xor(s, off);
    q += __shfl_xor(q, off);
  }
  __shared__ float sb[4], qb[4];
  int w = t >> 6, l = t & 63;
  if (l == 0) { sb[w] = s; qb[w] = q; }
  __syncthreads();
  s = sb[0] + sb[1] + sb[2] + sb[3];
  q = qb[0] + qb[1] + qb[2] + qb[3];
  float mean = s * (1.f / 1024.f);
  float var = q * (1.f / 1024.f) - mean * mean;
  float rs = rsqrtf(var + 1e-5f);
  float4 gv = *(const float4*)(g + t * 4);
  float4 bv = *(const float4*)(bt + t * 4);
  ushort4 o;
  o.x = f2bf((v0 - mean) * rs * gv.x + bv.x);
  o.y = f2bf((v1 - mean) * rs * gv.y + bv.y);
  o.z = f2bf((v2 - mean) * rs * gv.z + bv.z);
  o.w = f2bf((v3 - mean) * rs * gv.w + bv.w);
  *(ushort4*)(out + ((size_t)row << 10) + t * 4) = o;
}

// ---------------------------------------------------------------------------
// Double-buffered GEMM core 64x128, BK=64, compile-time strides.
// 48 KiB LDS -> 3 blocks/CU. Waves 1x4: wave w covers 64 rows x 32 cols.
// ---------------------------------------------------------------------------
template <int LDA, int LDB, int NKT>
__device__ __forceinline__ void gemm_core_db64(
    const u16* __restrict__ A, const u16* __restrict__ Bt,
    int bm, int bn, u16* lds, f32x4 acc[4][2]) {
  const int tid = threadIdx.x;
  const int w = tid >> 6, l = tid & 63;
  const int wn = w << 5;
  const int lrow = l >> 3;
  const int cg = (l & 7) ^ lrow;
  const u16* Ab = A + (size_t)(bm << 6) * LDA + (cg << 3);
  const u16* Bb = Bt + (size_t)(bn << 7) * LDB + (cg << 3);
#define GSTAGE64(T, BUF)                                                     \
  {                                                                          \
    const int kk = (T) << 6;                                                 \
    u16* la = lds + (BUF) * 12288;                                           \
    u16* lb = la + 4096;                                                     \
    _Pragma("unroll") for (int i = 0; i < 2; ++i) {                          \
      int c = (w << 1) + i;                                                  \
      int row = (c << 3) + lrow;                                             \
      gld_lds16(Ab + (size_t)row * LDA + kk, la + (c << 9));                 \
    }                                                                        \
    _Pragma("unroll") for (int i = 0; i < 4; ++i) {                          \
      int c = (w << 2) + i;                                                  \
      int row = (c << 3) + lrow;                                             \
      gld_lds16(Bb + (size_t)row * LDB + kk, lb + (c << 9));                 \
    }                                                                        \
  }
  GSTAGE64(0, 0);
  __syncthreads();
  for (int t = 0; t < NKT; ++t) {
    if (t + 1 < NKT) GSTAGE64(t + 1, (t & 1) ^ 1);
    const u16* la = lds + (t & 1) * 12288;
    const u16* lb = la + 4096;
    bf16x8 af[2][4], bfr[2][2];
    const int rr = l & 15;
    const int kgb = l >> 4;
#pragma unroll
    for (int ks = 0; ks < 2; ++ks) {
      const int kg = kgb + (ks << 2);
#pragma unroll
      for (int f = 0; f < 4; ++f) {
        int ra = (f << 4) + rr;
        af[ks][f] = *(const bf16x8*)(la + (ra << 6) + ((kg ^ (ra & 7)) << 3));
      }
#pragma unroll
      for (int f = 0; f < 2; ++f) {
        int rb = wn + (f << 4) + rr;
        bfr[ks][f] = *(const bf16x8*)(lb + (rb << 6) + ((kg ^ (rb & 7)) << 3));
      }
    }
#pragma unroll
    for (int fm = 0; fm < 4; ++fm)
#pragma unroll
      for (int fn = 0; fn < 2; ++fn)
#pragma unroll
        for (int ks = 0; ks < 2; ++ks)
          acc[fm][fn] = __builtin_amdgcn_mfma_f32_16x16x32_bf16(
              af[ks][fm], bfr[ks][fn], acc[fm][fn], 0, 0, 0);
    __syncthreads();
  }
#undef GSTAGE64
}

#define ACC_INIT64()                      \
  f32x4 acc[4][2];                        \
  { f32x4 zf = {0.f, 0.f, 0.f, 0.f};      \
_Pragma("unroll")                         \
    for (int a = 0; a < 4; ++a)           \
_Pragma("unroll")                         \
      for (int bb = 0; bb < 2; ++bb) acc[a][bb] = zf; }

#define EPI_SETUP64()                                   \
  const int w = threadIdx.x >> 6, l = threadIdx.x & 63; \
  const int wn = w << 5;

#define GEMM_LDS64() __shared__ __attribute__((aligned(16))) u16 lds[2 * 12288]

// --- QKV: 64-row tiles; all z write (b,h,s,d); z=2 -> vtmp; Q pre-scaled -----
__global__ void __launch_bounds__(256, 2) gemm_qkv(
    const u16* __restrict__ nx, const u16* __restrict__ wt,
    const float* __restrict__ bq, const float* __restrict__ bk,
    const float* __restrict__ bv, u16* __restrict__ qk, u16* __restrict__ vtmp) {
  GEMM_LDS64();
  ACC_INIT64();
  int z = blockIdx.z;
  const u16* Bt = wt + (size_t)z * 1024 * 1024;
  const float* bias = z == 0 ? bq : z == 1 ? bk : bv;
  u16* out = z == 2 ? vtmp : qk + (size_t)z * M_ * 1024;
  const float scl = (z == 0) ? 0.18033688f : 1.0f;  // 0.125*log2(e) for Q
  gemm_core_db64<1024, 1024, 16>(nx, Bt, blockIdx.x, blockIdx.y, lds, acc);
  EPI_SETUP64();
#pragma unroll
  for (int fm = 0; fm < 4; ++fm)
#pragma unroll
    for (int fn = 0; fn < 2; ++fn)
#pragma unroll
      for (int j = 0; j < 4; ++j) {
        int row = (blockIdx.x << 6) + (fm << 4) + ((l >> 4) << 2) + j;
        int col = (blockIdx.y << 7) + wn + (fn << 4) + (l & 15);
        float v = (acc[fm][fn][j] + bias[col]) * scl;
        int b = row >> 10, s = row & 1023;
        int h = col >> 6, d = col & 63;
        out[(((size_t)(b * 16 + h) << 10) + s) * 64 + d] = f2bf(v);
      }
}

// --- gnnV: xvg[b,q,e] = gnnbf[b] @ Vt[b]^T (bf16 out) ------------------------
__global__ void __launch_bounds__(256, 2) gemm_gnnv(
    const u16* __restrict__ gnnbf, const u16* __restrict__ vt,
    u16* __restrict__ xvg) {
  GEMM_LDS64();
  ACC_INIT64();
  int b = blockIdx.z;
  const u16* A = gnnbf + ((size_t)b << 20);
  const u16* Bt = vt + ((size_t)b << 20);
  u16* out = xvg + ((size_t)b << 20);
  gemm_core_db64<1024, 1024, 16>(A, Bt, blockIdx.x, blockIdx.y, lds, acc);
  EPI_SETUP64();
#pragma unroll
  for (int fm = 0; fm < 4; ++fm)
#pragma unroll
    for (int fn = 0; fn < 2; ++fn)
#pragma unroll
      for (int j = 0; j < 4; ++j) {
        int row = (blockIdx.x << 6) + (fm << 4) + ((l >> 4) << 2) + j;
        int col = (blockIdx.y << 7) + wn + (fn << 4) + (l & 15);
        out[((size_t)row << 10) + col] = f2bf(acc[fm][fn][j]);
      }
}

// --- Wo: x1b = bf16(x + xv@Wo + bo) ------------------------------------------
__global__ void __launch_bounds__(256, 2) gemm_wo(
    const u16* __restrict__ xv, const u16* __restrict__ wt,
    const float* __restrict__ bo, const float* __restrict__ xres,
    u16* __restrict__ x1b) {
  GEMM_LDS64();
  ACC_INIT64();
  gemm_core_db64<1024, 1024, 16>(xv, wt, blockIdx.x, blockIdx.y, lds, acc);
  EPI_SETUP64();
#pragma unroll
  for (int fm = 0; fm < 4; ++fm)
#pragma unroll
    for (int fn = 0; fn < 2; ++fn)
#pragma unroll
      for (int j = 0; j < 4; ++j) {
        int row = (blockIdx.x << 6) + (fm << 4) + ((l >> 4) << 2) + j;
        int col = (blockIdx.y << 7) + wn + (fn << 4) + (l & 15);
        size_t idx = ((size_t)row << 10) + col;
        x1b[idx] = f2bf(acc[fm][fn][j] + bo[col] + xres[idx]);
      }
}

// --- W1: ff1 = gelu(h@W1 + bf1) bf16 (M x FF), 64-row tiles ------------------
__global__ void __launch_bounds__(256, 2) gemm_w1(
    const u16* __restrict__ hb, const u16* __restrict__ wt,
    const float* __restrict__ bf1, u16* __restrict__ ff1) {
  GEMM_LDS64();
  ACC_INIT64();
  gemm_core_db64<1024, 1024, 16>(hb, wt, blockIdx.x, blockIdx.y, lds, acc);
  EPI_SETUP64();
#pragma unroll
  for (int fm = 0; fm < 4; ++fm)
#pragma unroll
    for (int fn = 0; fn < 2; ++fn)
#pragma unroll
      for (int j = 0; j < 4; ++j) {
        int row = (blockIdx.x << 6) + (fm << 4) + ((l >> 4) << 2) + j;
        int col = (blockIdx.y << 7) + wn + (fn << 4) + (l & 15);
        float v = acc[fm][fn][j] + bf1[col];
        float ge = 0.5f * v * (1.f + erff(v * 0.70710678118654752f));
        ff1[((size_t)row << 12) + col] = f2bf(ge);
      }
}

// --- W2: out = x1b + ff1@W2 + bf2 (fp32, K=4096), 64-row tiles ---------------
__global__ void __launch_bounds__(256, 2) gemm_w2(
    const u16* __restrict__ ff1, const u16* __restrict__ wt,
    const float* __restrict__ bf2, const u16* __restrict__ x1b,
    float* __restrict__ out) {
  GEMM_LDS64();
  ACC_INIT64();
  gemm_core_db64<4096, 4096, 64>(ff1, wt, blockIdx.x, blockIdx.y, lds, acc);
  EPI_SETUP64();
#pragma unroll
  for (int fm = 0; fm < 4; ++fm)
#pragma unroll
    for (int fn = 0; fn < 2; ++fn)
#pragma unroll
      for (int j = 0; j < 4; ++j) {
        int row = (blockIdx.x << 6) + (fm << 4) + ((l >> 4) << 2) + j;
        int col = (blockIdx.y << 7) + wn + (fn << 4) + (l & 15);
        size_t idx = ((size_t)row << 10) + col;
        out[idx] = acc[fm][fn][j] + bf2[col] + bf2f(x1b[idx]);
      }
}

// ---------------------------------------------------------------------------
// Flash attention, fixed-shift softmax (C=8, exp2 domain).
// Grid: 512 blocks (XCD-chunked); 4 waves x 32 q-rows; KV tile 64.
// ---------------------------------------------------------------------------
__global__ void __launch_bounds__(256, 2) attn_kernel(
    const u16* __restrict__ Q, const u16* __restrict__ K,
    const u16* __restrict__ Vt, const u16* __restrict__ biasI,
    const u16* __restrict__ xvg, u16* __restrict__ xv) {
  const int lin = ((blockIdx.x & 7) << 6) + (blockIdx.x >> 3);  // XCD chunk
  const int qt = lin & 7, h = (lin >> 3) & 15, b = lin >> 7;
  const int tid = threadIdx.x, w = tid >> 6, l = tid & 63;
  __shared__ __attribute__((aligned(16))) u16 kbuf[2][64 * 64];
  __shared__ __attribute__((aligned(16))) u16 vbuf[2][64 * 64];
  __shared__ __attribute__((aligned(16))) u16 pbuf[4][32 * 64];
  const size_t bh = ((size_t)(b * 16 + h)) << 16;
  const u16* Qb = Q + bh;
  const u16* Kb = K + bh;
  const u16* Vtb = Vt + ((size_t)b << 20) + ((size_t)(h * 64) << 10);
  const u16* biasb = biasI + ((size_t)b << 20);
  const int q0 = (qt << 7) + (w << 5);
  const int lrow = l >> 3, cg = (l & 7) ^ lrow;
  const int l4 = l >> 4, lo = l & 15;
  u16* p_w = pbuf[w];

  bf16x8 qf[2][2];
#pragma unroll
  for (int m = 0; m < 2; ++m)
#pragma unroll
    for (int ks = 0; ks < 2; ++ks)
      qf[m][ks] = *(const bf16x8*)(Qb + ((size_t)(q0 + m * 16 + lo) << 6) +
                                   l4 * 8 + ks * 32);
  bf16x8 onesf;
#pragma unroll
  for (int j = 0; j < 8; ++j) onesf[j] = (short)0x3F80;

  f32x4 osoft[2][4], osum[2];
  f32x4 zf = {0.f, 0.f, 0.f, 0.f};
#pragma unroll
  for (int m = 0; m < 2; ++m) {
    osum[m] = zf;
#pragma unroll
    for (int fd = 0; fd < 4; ++fd) osoft[m][fd] = zf;
  }

#define STAGE(T, BUF)                                                          \
  {                                                                            \
    int kv0s = (T) << 6;                                                       \
    u16* kd = &kbuf[BUF][0];                                                   \
    u16* vd = &vbuf[BUF][0];                                                   \
    _Pragma("unroll") for (int i = 0; i < 2; ++i) {                            \
      int c = (w << 1) + i;                                                    \
      gld_lds16(Kb + ((size_t)(kv0s + (c << 3) + lrow) << 6) + (cg << 3),      \
                kd + (c << 9));                                                \
      gld_lds16(Vtb + ((size_t)((c << 3) + lrow) << 10) + kv0s + (cg << 3),    \
                vd + (c << 9));                                                \
    }                                                                          \
  }

  STAGE(0, 0);
  __syncthreads();

  for (int t = 0; t < 16; ++t) {
    const int cur = t & 1;
    if (t < 15) STAGE(t + 1, cur ^ 1);
    const u16* kb_ = &kbuf[cur][0];
    const u16* vb_ = &vbuf[cur][0];
    // C-init from bias (holds -8 / -30008 in exp2 domain)
    f32x4 sacc[2][4];
#pragma unroll
    for (int m = 0; m < 2; ++m)
#pragma unroll
      for (int j = 0; j < 4; ++j) {
        ushort4 bb = *(const ushort4*)(
            biasb + (((size_t)(t * 1024 + q0 + m * 16 + l4 * 4 + j)) << 6) +
            lo * 4);
        sacc[m][0][j] = bf2f(bb.x);
        sacc[m][1][j] = bf2f(bb.y);
        sacc[m][2][j] = bf2f(bb.z);
        sacc[m][3][j] = bf2f(bb.w);
      }
    // QK^T
    __builtin_amdgcn_s_setprio(1);
#pragma unroll
    for (int ks = 0; ks < 2; ++ks) {
      const int kg = l4 + (ks << 2);
      bf16x8 kf[4];
#pragma unroll
      for (int fn = 0; fn < 4; ++fn) {
        int rk = (fn << 4) + lo;
        kf[fn] = *(const bf16x8*)(kb_ + (rk << 6) + ((kg ^ (rk & 7)) << 3));
      }
#pragma unroll
      for (int m = 0; m < 2; ++m)
#pragma unroll
        for (int fn = 0; fn < 4; ++fn)
          sacc[m][fn] = __builtin_amdgcn_mfma_f32_16x16x32_bf16(
              qf[m][ks], kf[fn], sacc[m][fn], 0, 0, 0);
    }
    __builtin_amdgcn_s_setprio(0);
    // P = exp2(s), pack to bf16, store to per-wave LDS
#pragma unroll
    for (int m = 0; m < 2; ++m)
#pragma unroll
      for (int fn = 0; fn < 4; ++fn)
#pragma unroll
        for (int j = 0; j < 4; ++j) {
          float p = exp2f(sacc[m][fn][j]);
          unsigned int u = __builtin_bit_cast(unsigned int, p);
          int prow = (m << 4) + (l4 << 2) + j;
          int pcol = (fn << 4) + lo;
          p_w[(prow << 6) + (pcol ^ ((prow & 7) << 3))] =
              (u16)((u + 0x8000u) >> 16);
        }
    // PV + ones-column rowsum
    __builtin_amdgcn_s_setprio(1);
#pragma unroll
    for (int ks = 0; ks < 2; ++ks) {
      const int kg = l4 + (ks << 2);
      bf16x8 pf[2], vf[4];
#pragma unroll
      for (int m = 0; m < 2; ++m) {
        int pr = (m << 4) + lo;
        pf[m] = *(const bf16x8*)(p_w + (pr << 6) + ((kg ^ (pr & 7)) << 3));
      }
#pragma unroll
      for (int fd = 0; fd < 4; ++fd) {
        int rd = (fd << 4) + lo;
        vf[fd] = *(const bf16x8*)(vb_ + (rd << 6) + ((kg ^ (rd & 7)) << 3));
      }
#pragma unroll
      for (int m = 0; m < 2; ++m) {
        osum[m] = __builtin_amdgcn_mfma_f32_16x16x32_bf16(
            pf[m], onesf, osum[m], 0, 0, 0);
#pragma unroll
        for (int fd = 0; fd < 4; ++fd)
          osoft[m][fd] = __builtin_amdgcn_mfma_f32_16x16x32_bf16(
              pf[m], vf[fd], osoft[m][fd], 0, 0, 0);
      }
    }
    __builtin_amdgcn_s_setprio(0);
    __syncthreads();
  }
  // epilogue
#pragma unroll
  for (int m = 0; m < 2; ++m) {
    f32x4 rl;
#pragma unroll
    for (int j = 0; j < 4; ++j) rl[j] = 1.0f / osum[m][j];
#pragma unroll
    for (int fd = 0; fd < 4; ++fd)
#pragma unroll
      for (int j = 0; j < 4; ++j) {
        int qrow = q0 + (m << 4) + (l4 << 2) + j;
        int e = (h << 6) + (fd << 4) + lo;
        size_t idx = (((size_t)(b * 1024 + qrow)) << 10) + e;
        float o = osoft[m][fd][j] * rl[j] + bf2f(xvg[idx]);
        xv[idx] = f2bf(o);
      }
  }
#undef STAGE
}

// ---------------------------------------------------------------------------
extern "C" void kernel_launch(void* const* d_in, const int* in_sizes, int n_in,
                              void* d_out, int out_size, void* d_ws, size_t ws_size,
                              hipStream_t stream) {
  (void)in_sizes; (void)n_in; (void)out_size; (void)ws_size;
  const float* x   = (const float*)d_in[0];
  const float* mask= (const float*)d_in[1];
  const float* gnn = (const float*)d_in[2];
  const float* Wq  = (const float*)d_in[3];
  const float* bq  = (const float*)d_in[4];
  const float* Wk  = (const float*)d_in[5];
  const float* bk  = (const float*)d_in[6];
  const float* Wv  = (const float*)d_in[7];
  const float* bv  = (const float*)d_in[8];
  const float* Wo  = (const float*)d_in[9];
  const float* bo  = (const float*)d_in[10];
  const float* g1  = (const float*)d_in[11];
  const float* b1  = (const float*)d_in[12];
  const float* g2  = (const float*)d_in[13];
  const float* b2  = (const float*)d_in[14];
  const float* W1  = (const float*)d_in[15];
  const float* bf1 = (const float*)d_in[16];
  const float* W2  = (const float*)d_in[17];
  const float* bf2 = (const float*)d_in[18];
  float* out = (float*)d_out;

  char* ws = (char*)d_ws;
  const size_t MB = 1024 * 1024;
  // layout (MB): 0-24 wt | 24-32 nx -> xvbuf -> hbuf | 32-40 Q | 40-48 K
  // | 48-56 Vt | 56-64 biasI | 64-72 gnnbf -> x1b | 72-80 vtmp -> xvg
  // post-attn: ff1 32-64
  u16*  wt    = (u16*)(ws);
  u16*  nx    = (u16*)(ws + 24 * MB);
  u16*  xvbuf = (u16*)(ws + 24 * MB);
  u16*  hbuf  = (u16*)(ws + 24 * MB);
  u16*  qk    = (u16*)(ws + 32 * MB);
  u16*  vt    = (u16*)(ws + 48 * MB);
  u16*  biasI = (u16*)(ws + 56 * MB);
  u16*  gnnbf = (u16*)(ws + 64 * MB);
  u16*  x1b   = (u16*)(ws + 64 * MB);
  u16*  vtmp  = (u16*)(ws + 72 * MB);
  u16*  xvg   = (u16*)(ws + 72 * MB);
  u16*  ff1   = (u16*)(ws + 32 * MB);

  pre_kernel<<<20480, 256, 0, stream>>>(Wq, Wk, Wv, Wo, W1, W2, wt,
                                        x, g1, b1, nx, mask, gnn, biasI, gnnbf);
  gemm_qkv<<<dim3(64, 8, 3), 256, 0, stream>>>(nx, wt, bq, bk, bv, qk, vtmp);
  vtrans_kernel<<<dim3(16, 16, 4), 256, 0, stream>>>(vtmp, vt);
  gemm_gnnv<<<dim3(16, 8, 4), 256, 0, stream>>>(gnnbf, vt, xvg);
  attn_kernel<<<512, 256, 0, stream>>>(
      qk, qk + (size_t)4 * MB, vt, biasI, xvg, xvbuf);
  gemm_wo<<<dim3(64, 8), 256, 0, stream>>>(xvbuf, wt + (size_t)3 * MB, bo, x, x1b);
  ln_kernel_b<<<4096, 256, 0, stream>>>(x1b, g2, b2, hbuf);
  gemm_w1<<<dim3(64, 32), 256, 0, stream>>>(hbuf, wt + (size_t)4 * MB, bf1, ff1);
  gemm_w2<<<dim3(64, 8), 256, 0, stream>>>(ff1, wt + (size_t)8 * MB, bf2, x1b, out);
}